// Round 5
// baseline (744.087 us; speedup 1.0000x reference)
//
#include <hip/hip_runtime.h>
#include <hip/hip_bf16.h>
#include <math.h>

#define I48 0.14433756729740643f  // 1/sqrt(48)
#define NKB 194                   // 6144 W rows + 64 bias rows, /32
#define KCH 4                     // kblks per LDS chunk (12 KiB fp16)
#define KSPL 6                    // K-split across blockIdx.y

typedef __attribute__((ext_vector_type(8))) _Float16 half8;
typedef __attribute__((ext_vector_type(4))) float f32x4;

__device__ __forceinline__ float silu_f(float x){ return x / (1.f + __expf(-x)); }

// ---------------- time embedding (1 block, 128 thr) ----------------
__global__ void k_temb(const float* __restrict__ t_in,
                       const float* __restrict__ w1, const float* __restrict__ b1,
                       const float* __restrict__ w2, const float* __restrict__ b2,
                       const float* __restrict__ g,  const float* __restrict__ b,
                       float* __restrict__ temb){
  __shared__ float emb[64], h1[128], red[128];
  __shared__ float s_mu, s_rs;
  int t = threadIdx.x;
  float tv = t_in[0];
  if (t < 64){
    int i = t & 31;
    float fr = __expf((float)i * (-9.210340371976184f/31.f));
    float a = tv * fr;
    emb[t] = (t < 32) ? sinf(a) : cosf(a);
  }
  __syncthreads();
  {
    float z = b1[t];
    for (int i=0;i<64;i++) z += emb[i]*w1[i*128+t];
    h1[t] = silu_f(z);
  }
  __syncthreads();
  float tp = 0.f;
  if (t < 64){
    tp = b2[t];
    for (int j=0;j<128;j++) tp += h1[j]*w2[j*64+t];
  }
  red[t] = (t<64)? tp : 0.f;
  __syncthreads();
  for (int st=64;st;st>>=1){ if(t<st) red[t]+=red[t+st]; __syncthreads(); }
  if (t==0) s_mu = red[0]/64.f;
  __syncthreads();
  float d = tp - s_mu;
  red[t] = (t<64)? d*d : 0.f;
  __syncthreads();
  for (int st=64;st;st>>=1){ if(t<st) red[t]+=red[t+st]; __syncthreads(); }
  if (t==0) s_rs = rsqrtf(red[0]/64.f + 1e-5f);
  __syncthreads();
  if (t<64) temb[t] = g[t]*(d*s_rs) + b[t];
}

// ---------------- node encoders: x(in_dim) -> LN128 -> silu -> 48 ----------------
__global__ void k_enc(const float* __restrict__ x, int in_dim,
                      const float* __restrict__ w1, const float* __restrict__ b1,
                      const float* __restrict__ g,  const float* __restrict__ bb,
                      const float* __restrict__ w2, const float* __restrict__ b2,
                      float* __restrict__ out, int row_off){
  __shared__ float sx[96], sh[128], red[128];
  __shared__ float s_mu, s_rs;
  int row = blockIdx.x, t = threadIdx.x;
  for (int i=t;i<in_dim;i+=128) sx[i] = x[(size_t)row*in_dim+i];
  __syncthreads();
  float z = b1[t];
  for (int i=0;i<in_dim;i++) z += sx[i]*w1[i*128+t];
  red[t]=z; __syncthreads();
  for (int st=64;st;st>>=1){ if(t<st) red[t]+=red[t+st]; __syncthreads(); }
  if(!t) s_mu = red[0]/128.f;
  __syncthreads();
  float d = z - s_mu;
  red[t]=d*d; __syncthreads();
  for (int st=64;st;st>>=1){ if(t<st) red[t]+=red[t+st]; __syncthreads(); }
  if(!t) s_rs = rsqrtf(red[0]/128.f+1e-5f);
  __syncthreads();
  float h = g[t]*(d*s_rs)+bb[t];
  sh[t] = silu_f(h);
  __syncthreads();
  if (t<48){
    float o = b2[t];
    for (int j=0;j<128;j++) o += sh[j]*w2[j*48+t];
    out[(size_t)(row_off+row)*48+t] = o;
  }
}

// ---------------- s0 = (enc @ sp_w + sp_b) @ emb_w * I48 ----------------
__global__ void k_s0(const float* __restrict__ enc, const float* __restrict__ spw,
                     const float* __restrict__ spb, const float* __restrict__ embw,
                     float* __restrict__ s){
  __shared__ float se[48], sc[48];
  int n = blockIdx.x, t = threadIdx.x;
  if (t<48) se[t] = enc[(size_t)n*48+t];
  __syncthreads();
  if (t<48){
    float c = spb[t];
    for (int i=0;i<48;i++) c += se[i]*spw[i*48+t];
    sc[t] = c;
  }
  __syncthreads();
  if (t<48){
    float v = 0.f;
    for (int i=0;i<48;i++) v += sc[i]*embw[i*48+t];
    s[(size_t)n*48+t] = v*I48;
  }
}

// ---------------- per-edge: dist -> ef(32); also degree atomics ----------------
__global__ void k_edge(const float* __restrict__ lc, const float* __restrict__ pc,
                       const int* __restrict__ src, const int* __restrict__ dst,
                       const float* __restrict__ temb,
                       const float* __restrict__ w1, const float* __restrict__ b1,
                       const float* __restrict__ w2, const float* __restrict__ b2,
                       float* __restrict__ ef, float* __restrict__ degf,
                       int E, int Nl){
  __shared__ float sh_h[2][32];
  int t = threadIdx.x, sub = t>>5, j = t&31;
  int e = blockIdx.x*2 + sub;
  if (e < E){
    int s_ = src[e], d_ = dst[e];
    float vx = lc[(size_t)s_*3+0]-pc[(size_t)d_*6+0];
    float vy = lc[(size_t)s_*3+1]-pc[(size_t)d_*6+1];
    float vz = lc[(size_t)s_*3+2]-pc[(size_t)d_*6+2];
    float dist = sqrtf(vx*vx+vy*vy+vz*vz+1e-12f);
    float h = b1[j] + dist*w1[j];
    for (int a=0;a<64;a++) h += temb[a]*w1[(a+1)*32+j];
    sh_h[sub][j] = silu_f(h);
  }
  __syncthreads();
  if (e < E){
    float o = b2[j];
    for (int a=0;a<32;a++) o += sh_h[sub][a]*w2[a*32+j];
    ef[(size_t)e*32+j] = o;
    if (j==0) atomicAdd(&degf[Nl + dst[e]], 1.f);
  }
}

// ---------------- pack conv MLP weights into MFMA B-fragment order, fp16 ----------------
__global__ void k_packMLP(const float* __restrict__ w1, const float* __restrict__ w2,
                          _Float16* __restrict__ w1p, _Float16* __restrict__ w2p, int L){
  int tot1 = L*8*512;
  int tot2 = L*32*512;
  int total = tot1 + tot2;
  for (int idx = blockIdx.x*blockDim.x+threadIdx.x; idx < total; idx += gridDim.x*blockDim.x){
    if (idx < tot1){
      int j = idx & 7, lane = (idx>>3)&63, rest = idx>>9;
      int nt = rest & 7, l = rest >> 3;
      int k = (lane>>4)*8 + j, o = nt*16 + (lane&15);
      w1p[idx] = (_Float16)w1[((size_t)l*32 + k)*128 + o];
    } else {
      int i2 = idx - tot1;
      int j = i2 & 7, lane = (i2>>3)&63, rest = i2>>9;
      int nt = rest & 7, kb = (rest>>3)&3, l = rest >> 5;
      int k = kb*32 + (lane>>4)*8 + j, o = nt*16 + (lane&15);
      w2p[i2] = (_Float16)w2[((size_t)l*128 + k)*128 + o];
    }
  }
}

// ---------------- edge MLP via MFMA: 64 edges x 1 layer per block ----------------
__global__ __launch_bounds__(256) void k_mlp2(
    const float* __restrict__ ef,
    const _Float16* __restrict__ w1p, const float* __restrict__ b1a,
    const _Float16* __restrict__ w2p, const float* __restrict__ b2a,
    _Float16* __restrict__ m2h, int E){
  __shared__ __align__(16) _Float16 sef[64][40];
  __shared__ __align__(16) _Float16 shh[64][136];
  __shared__ float sb1[128], sb2[128];
  const int t = threadIdx.x, lane = t & 63, w = t >> 6;
  const int e0 = blockIdx.x * 64;
  const int l  = blockIdx.y;
  const _Float16* w1l = w1p + (size_t)l*4096;
  const _Float16* w2l = w2p + (size_t)l*16384;
  if (t < 128) sb1[t] = b1a[l*128 + t];
  else         sb2[t-128] = b2a[l*128 + (t-128)];
  {
    int row = t >> 2, g = t & 3;
    const float* p = ef + ((size_t)(e0+row))*32 + g*8;
    float4 p0 = *(const float4*)p, p1 = *(const float4*)(p+4);
    half8 hv;
    hv[0]=(_Float16)p0.x; hv[1]=(_Float16)p0.y; hv[2]=(_Float16)p0.z; hv[3]=(_Float16)p0.w;
    hv[4]=(_Float16)p1.x; hv[5]=(_Float16)p1.y; hv[6]=(_Float16)p1.z; hv[7]=(_Float16)p1.w;
    *(half8*)&sef[row][g*8] = hv;
  }
  __syncthreads();
  const int m = lane & 15, quad = lane >> 4;
  const int r = w*16 + m;
  half8 a1 = *(const half8*)&sef[r][quad*8];
  f32x4 acc1[8];
  #pragma unroll
  for (int nt=0; nt<8; nt++){
    half8 b = *(const half8*)(w1l + (nt*64 + lane)*8);
    f32x4 z = {0.f,0.f,0.f,0.f};
    acc1[nt] = __builtin_amdgcn_mfma_f32_16x16x32_f16(a1, b, z, 0,0,0);
  }
  #pragma unroll
  for (int nt=0; nt<8; nt++){
    float bv = sb1[nt*16 + m];
    #pragma unroll
    for (int rr=0; rr<4; rr++)
      shh[w*16 + quad*4 + rr][nt*16 + m] = (_Float16)silu_f(acc1[nt][rr] + bv);
  }
  __syncthreads();
  f32x4 acc2[8];
  #pragma unroll
  for (int nt=0;nt<8;nt++) acc2[nt] = (f32x4){0.f,0.f,0.f,0.f};
  #pragma unroll
  for (int kb=0; kb<4; kb++){
    half8 a2 = *(const half8*)&shh[r][kb*32 + quad*8];
    #pragma unroll
    for (int nt=0; nt<8; nt++){
      half8 b = *(const half8*)(w2l + ((size_t)(kb*8+nt)*64 + lane)*8);
      acc2[nt] = __builtin_amdgcn_mfma_f32_16x16x32_f16(a2, b, acc2[nt], 0,0,0);
    }
  }
  __syncthreads();
  #pragma unroll
  for (int nt=0; nt<8; nt++){
    float bv = sb2[nt*16 + m];
    #pragma unroll
    for (int rr=0; rr<4; rr++)
      shh[w*16 + quad*4 + rr][nt*16 + m] = (_Float16)silu_f(acc2[nt][rr] + bv);
  }
  __syncthreads();
  for (int q = t; q < 64*16; q += 256){
    int row = q >> 4, c = q & 15;
    half8 hv = *(const half8*)&shh[row][c*8];
    *(half8*)(m2h + ((size_t)l*E + e0 + row)*128 + c*8) = hv;
  }
}

// ---------------- pack W (+bias rows): READ-coalesced, scattered 2B writes ----------------
// source Wss slice: w3[(l*128+kk)*11520 + i*48 + o], contiguous r = i*48+o in [0,2304)
// dest fragment: kp = i*128+kk; kblk=kp>>5; p=kp&31; lane=(p>>3)*16+(o&15); j=p&7; nt=o>>4
__global__ void k_packB2(const float* __restrict__ w3, const float* __restrict__ b3,
                         _Float16* __restrict__ wbh, int L){
  int tot1 = L*128*2304;
  int tot2 = L*64*48;
  int total = tot1 + tot2;
  for (int idx = blockIdx.x*blockDim.x+threadIdx.x; idx < total; idx += gridDim.x*blockDim.x){
    if (idx < tot1){
      int r = idx % 2304; int q = idx / 2304;
      int kk = q & 127;   int l = q >> 7;
      float v = w3[(size_t)(l*128+kk)*11520 + r];
      int i = r / 48, o = r - i*48;
      int kp = i*128 + kk;
      int kblk = kp >> 5, p = kp & 31;
      int lane = ((p>>3)<<4) + (o & 15);
      int j = p & 7;
      int nt = o >> 4;
      wbh[((((size_t)l*NKB + kblk)*3 + nt)*64 + lane)*8 + j] = (_Float16)v;
    } else {
      int i2 = idx - tot1;
      int o = i2 % 48; int q = i2 / 48;
      int ii = q & 63; int l = q >> 6;
      float v = (ii < 48) ? b3[(size_t)l*11520 + ii*48 + o] : 0.f;
      int kp = 6144 + ii;
      int kblk = kp >> 5, p = kp & 31;
      int lane = ((p>>3)<<4) + (o & 15);
      int j = p & 7;
      int nt = o >> 4;
      wbh[((((size_t)l*NKB + kblk)*3 + nt)*64 + lane)*8 + j] = (_Float16)v;
    }
  }
}

// ---------------- hot kernel: fp16 MFMA GEMM, 128 edges x K-range per block ----------------
__global__ __launch_bounds__(256) void k_msg4(
    const _Float16* __restrict__ m2h, const float* __restrict__ s,
    const _Float16* __restrict__ wbh,
    const int* __restrict__ src, const int* __restrict__ dst,
    float* __restrict__ Sacc, int Nl){
  __shared__ __align__(16) _Float16 sB[2][KCH*1536];   // 2 x 12 KiB
  __shared__ __align__(16) _Float16 sm2h[128][136];    // 34.8 KiB
  __shared__ __align__(16) _Float16 sseq[128][72];     // 18.4 KiB
  __shared__ int sdst[128];
  const int t = threadIdx.x, lane = t & 63, w = t >> 6;
  const int e0 = blockIdx.x * 128;
  const int by = blockIdx.y;
  const int kb0 = (NKB*by)/KSPL, kb1 = (NKB*(by+1))/KSPL;

  for (int q = t; q < 128*16; q += 256){
    int e = q >> 4, c = q & 15;
    float4 v = *(const float4*)(m2h + ((size_t)(e0+e))*128 + c*8);
    *(float4*)&sm2h[e][c*8] = v;
  }
  for (int q = t; q < 128*9; q += 256){
    int e = q/9, g = q - e*9;
    half8 hv = {};
    if (g < 6){
      const float* sp = s + (size_t)src[e0+e]*48 + g*8;
      float4 p0 = *(const float4*)sp, p1 = *(const float4*)(sp+4);
      hv[0]=(_Float16)p0.x; hv[1]=(_Float16)p0.y; hv[2]=(_Float16)p0.z; hv[3]=(_Float16)p0.w;
      hv[4]=(_Float16)p1.x; hv[5]=(_Float16)p1.y; hv[6]=(_Float16)p1.z; hv[7]=(_Float16)p1.w;
    }
    *(half8*)&sseq[e][g*8] = hv;
  }
  if (t < 128) sdst[t] = dst[e0+t];

  auto stage = [&](int c){
    int kbase = kb0 + c*KCH;
    int nk = kb1 - kbase; if (nk > KCH) nk = KCH;
    int bytes = nk*3072;
    const char* g = (const char*)wbh + (size_t)kbase*3072;
    char* lb = (char*)sB[c&1];
    for (int off = w*1024; off < bytes; off += 4096){
      __builtin_amdgcn_global_load_lds(
        (const __attribute__((address_space(1))) void*)(g + off + (size_t)lane*16),
        (__attribute__((address_space(3))) void*)(lb + off), 16, 0, 0);
    }
  };
  stage(0);

  const int m = lane & 15, quad = lane >> 4;
  const int r0 = w*32 + m, r1 = r0 + 16;
  f32x4 acc00={0.f,0.f,0.f,0.f}, acc01={0.f,0.f,0.f,0.f}, acc02={0.f,0.f,0.f,0.f};
  f32x4 acc10={0.f,0.f,0.f,0.f}, acc11={0.f,0.f,0.f,0.f}, acc12={0.f,0.f,0.f,0.f};

  const int nch = (kb1-kb0+KCH-1)/KCH;
  for (int c = 0; c < nch; c++){
    __syncthreads();
    if (c+1 < nch) stage(c+1);
    int kbase = kb0 + c*KCH;
    int kbn = kb1 - kbase; if (kbn > KCH) kbn = KCH;
    const _Float16* bb = sB[c&1];
    for (int kk = 0; kk < kbn; kk++){
      int kblk = kbase + kk;
      half8 a0, a1;
      if (kblk < 192){
        int i = kblk >> 2;
        int base = ((kblk & 3) << 5) + quad*8;
        _Float16 sv0 = sseq[r0][i], sv1 = sseq[r1][i];
        half8 m0 = *(const half8*)&sm2h[r0][base];
        half8 m1 = *(const half8*)&sm2h[r1][base];
        half8 s0v = {sv0,sv0,sv0,sv0,sv0,sv0,sv0,sv0};
        half8 s1v = {sv1,sv1,sv1,sv1,sv1,sv1,sv1,sv1};
        a0 = m0 * s0v;
        a1 = m1 * s1v;
      } else {
        int ib = ((kblk-192) << 5) + quad*8;
        a0 = *(const half8*)&sseq[r0][ib];
        a1 = *(const half8*)&sseq[r1][ib];
      }
      const _Float16* bk = bb + kk*1536 + lane*8;
      half8 b0 = *(const half8*)(bk);
      half8 b1 = *(const half8*)(bk + 512);
      half8 b2 = *(const half8*)(bk + 1024);
      acc00 = __builtin_amdgcn_mfma_f32_16x16x32_f16(a0, b0, acc00, 0, 0, 0);
      acc01 = __builtin_amdgcn_mfma_f32_16x16x32_f16(a0, b1, acc01, 0, 0, 0);
      acc02 = __builtin_amdgcn_mfma_f32_16x16x32_f16(a0, b2, acc02, 0, 0, 0);
      acc10 = __builtin_amdgcn_mfma_f32_16x16x32_f16(a1, b0, acc10, 0, 0, 0);
      acc11 = __builtin_amdgcn_mfma_f32_16x16x32_f16(a1, b1, acc11, 0, 0, 0);
      acc12 = __builtin_amdgcn_mfma_f32_16x16x32_f16(a1, b2, acc12, 0, 0, 0);
    }
  }
  #pragma unroll
  for (int r = 0; r < 4; r++){
    int el0 = w*32 + quad*4 + r;
    int el1 = el0 + 16;
    float* p0 = Sacc + (size_t)(Nl + sdst[el0])*48 + m;
    float* p1 = Sacc + (size_t)(Nl + sdst[el1])*48 + m;
    atomicAdd(p0 +  0, acc00[r]*I48);
    atomicAdd(p0 + 16, acc01[r]*I48);
    atomicAdd(p0 + 32, acc02[r]*I48);
    atomicAdd(p1 +  0, acc10[r]*I48);
    atomicAdd(p1 + 16, acc11[r]*I48);
    atomicAdd(p1 + 32, acc12[r]*I48);
  }
}

// ---------------- node update: a_s = Sacc/deg + s@si_ws*I48 ; BN partials ----------------
__global__ __launch_bounds__(256) void k_node(const float* __restrict__ Sacc,
                       const float* __restrict__ degf,
                       const float* __restrict__ s, const float* __restrict__ siw,
                       float* __restrict__ a_s, float* __restrict__ bnpart, int N){
  __shared__ float sh_s[16][48];
  __shared__ float sw[2304];
  __shared__ float csum[48], csq[48];
  int t = threadIdx.x;
  int n0 = blockIdx.x*16;
  for (int q=t;q<2304;q+=256) sw[q] = siw[q];
  for (int q=t;q<768;q+=256){
    int nl=q/48, i=q-nl*48;
    sh_s[nl][i] = s[(size_t)(n0+nl)*48+i];
  }
  if (t<48){ csum[t]=0.f; csq[t]=0.f; }
  __syncthreads();
  int nl = t>>4;
  int ob = (t&15)*3;
  int n = n0+nl;
  float dg = degf[n]; if (dg < 1.f) dg = 1.f;
  float inv = 1.f/dg;
  #pragma unroll
  for (int j=0;j<3;j++){
    int o = ob+j;
    float acc = 0.f;
    for (int i=0;i<48;i++) acc += sh_s[nl][i]*sw[i*48+o];
    float a = Sacc[(size_t)n*48+o]*inv + acc*I48;
    a_s[(size_t)n*48+o] = a;
    atomicAdd(&csum[o], a);
    atomicAdd(&csq[o], a*a);
  }
  __syncthreads();
  if (t<96) bnpart[(size_t)blockIdx.x*96 + t] = (t<48) ? csum[t] : csq[t-48];
}

// ---------------- fused: BN finalize (redundant per-block) + s update + Sacc zero ----------------
__global__ __launch_bounds__(256) void k_supd2(
    float* __restrict__ s, float* __restrict__ Sacc,
    const float* __restrict__ a_s, const float* __restrict__ bnpart,
    const float* __restrict__ g, const float* __restrict__ b,
    int nblk, int N){
  __shared__ float red[2][96];
  __shared__ float ksc[48], kbs[48];
  int t = threadIdx.x;
  if (t < 192){
    int gg = t/96, o = t - gg*96;
    float acc = 0.f;
    for (int bk=gg; bk<nblk; bk+=2) acc += bnpart[(size_t)bk*96 + o];
    red[gg][o] = acc;
  }
  __syncthreads();
  if (t < 48){
    float su = red[0][t] + red[1][t];
    float sq = red[0][48+t] + red[1][48+t];
    float mu  = su/(float)N;
    float var = sq/(float)N - mu*mu;
    float r = rsqrtf(var + 1e-5f);
    float sc = g[t]*r;
    ksc[t] = sc;
    kbs[t] = b[t] - mu*sc;
  }
  __syncthreads();
  int n0 = blockIdx.x*16;
  for (int q=t; q<768; q+=256){
    int o = q % 48;
    size_t idx = (size_t)n0*48 + q;
    s[idx] += a_s[idx]*ksc[o] + kbs[o];
    Sacc[idx] = 0.f;
  }
}

// ---------------- output ----------------
__global__ void k_out(const float* __restrict__ s, const float* __restrict__ ows,
                      float* __restrict__ out){
  __shared__ float sh_s[48];
  int n = blockIdx.x, t = threadIdx.x;
  if (t<48) sh_s[t] = s[(size_t)n*48+t];
  __syncthreads();
  float acc = 0.f;
  for (int i=0;i<48;i++) acc += sh_s[i]*ows[i*256+t];
  out[(size_t)n*259 + 3 + t] = acc*I48;
  if (t<3) out[(size_t)n*259 + t] = 0.f;
}

extern "C" void kernel_launch(void* const* d_in, const int* in_sizes, int n_in,
                              void* d_out, int out_size, void* d_ws, size_t ws_size,
                              hipStream_t stream){
  const float* protein_coords   = (const float*)d_in[0];
  const float* protein_features = (const float*)d_in[1];
  const float* ligand_coords    = (const float*)d_in[2];
  const float* ligand_features  = (const float*)d_in[3];
  const float* t_in    = (const float*)d_in[4];
  const float* te_w1   = (const float*)d_in[5];
  const float* te_b1   = (const float*)d_in[6];
  const float* te_w2   = (const float*)d_in[7];
  const float* te_b2   = (const float*)d_in[8];
  const float* te_ln_g = (const float*)d_in[9];
  const float* te_ln_b = (const float*)d_in[10];
  const float* pe_w1   = (const float*)d_in[11];
  const float* pe_b1   = (const float*)d_in[12];
  const float* pe_ln_g = (const float*)d_in[13];
  const float* pe_ln_b = (const float*)d_in[14];
  const float* pe_w2   = (const float*)d_in[15];
  const float* pe_b2   = (const float*)d_in[16];
  const float* le_w1   = (const float*)d_in[17];
  const float* le_b1   = (const float*)d_in[18];
  const float* le_ln_g = (const float*)d_in[19];
  const float* le_ln_b = (const float*)d_in[20];
  const float* le_w2   = (const float*)d_in[21];
  const float* le_b2   = (const float*)d_in[22];
  const float* sp_w    = (const float*)d_in[23];
  const float* sp_b    = (const float*)d_in[24];
  const float* emb_w   = (const float*)d_in[25];
  const float* ee_w1   = (const float*)d_in[26];
  const float* ee_b1   = (const float*)d_in[27];
  const float* ee_w2   = (const float*)d_in[28];
  const float* ee_b2   = (const float*)d_in[29];
  const float* conv_w1 = (const float*)d_in[30];
  const float* conv_b1 = (const float*)d_in[31];
  const float* conv_w2 = (const float*)d_in[32];
  const float* conv_b2 = (const float*)d_in[33];
  const float* conv_w3 = (const float*)d_in[34];
  const float* conv_b3 = (const float*)d_in[35];
  const float* bn_gs   = (const float*)d_in[36];
  const float* bn_bs   = (const float*)d_in[37];
  const float* si_ws   = (const float*)d_in[40];
  const float* out_ws  = (const float*)d_in[43];
  const int* edge_src  = (const int*)d_in[45];
  const int* edge_dst  = (const int*)d_in[46];

  int Np = in_sizes[0]/6;
  int Nl = in_sizes[2]/3;
  int E  = in_sizes[45];
  int N  = Nl+Np;
  int L  = in_sizes[36]/48;

  float* W = (float*)d_ws;
  size_t off = 0;
  auto alloc = [&](size_t n)->float*{ float* p = W+off; off += (n+63)&~(size_t)63; return p; };
  float* temb  = alloc(64);
  float* enc   = alloc((size_t)N*48);
  float* sbuf  = alloc((size_t)N*48);
  float* ef    = alloc((size_t)E*32);
  float* degf  = alloc(N);
  float* Sacc  = alloc((size_t)N*48);
  float* a_s   = alloc((size_t)N*48);
  float* bnpart= alloc((size_t)(N/16)*96);
  float* kscale= alloc(64);
  float* kbias = alloc(64);
  _Float16* m2h = (_Float16*)alloc((size_t)L*E*128/2 + 64);
  _Float16* wbh = (_Float16*)alloc((size_t)L*NKB*1536/2 + 64);
  _Float16* w1p = (_Float16*)alloc((size_t)L*4096/2 + 64);
  _Float16* w2p = (_Float16*)alloc((size_t)L*16384/2 + 64);
  (void)kscale; (void)kbias;

  hipMemsetAsync(degf, 0, (size_t)N*sizeof(float), stream);
  hipMemsetAsync(Sacc, 0, (size_t)N*48*sizeof(float), stream);
  k_packB2<<<2048,256,0,stream>>>(conv_w3, conv_b3, wbh, L);
  k_packMLP<<<480,256,0,stream>>>(conv_w1, conv_w2, w1p, w2p, L);
  k_temb<<<1,128,0,stream>>>(t_in, te_w1, te_b1, te_w2, te_b2, te_ln_g, te_ln_b, temb);
  k_enc<<<Np,128,0,stream>>>(protein_features, 96, pe_w1, pe_b1, pe_ln_g, pe_ln_b, pe_w2, pe_b2, enc, Nl);
  k_enc<<<Nl,128,0,stream>>>(ligand_features, 52, le_w1, le_b1, le_ln_g, le_ln_b, le_w2, le_b2, enc, 0);
  k_s0<<<N,64,0,stream>>>(enc, sp_w, sp_b, emb_w, sbuf);
  k_edge<<<(E+1)/2,64,0,stream>>>(ligand_coords, protein_coords, edge_src, edge_dst, temb,
                                  ee_w1, ee_b1, ee_w2, ee_b2, ef, degf, E, Nl);
  dim3 mlpg(E/64, L);
  k_mlp2<<<mlpg,256,0,stream>>>(ef, w1p, conv_b1, w2p, conv_b2, m2h, E);

  dim3 mgrid(E/128, KSPL);
  for (int l=0;l<L;l++){
    k_msg4<<<mgrid,256,0,stream>>>(m2h + (size_t)l*E*128, sbuf, wbh + (size_t)l*NKB*1536,
                                   edge_src, edge_dst, Sacc, Nl);
    k_node<<<N/16,256,0,stream>>>(Sacc, degf, sbuf, si_ws + (size_t)l*2304, a_s, bnpart, N);
    k_supd2<<<N/16,256,0,stream>>>(sbuf, Sacc, a_s, bnpart, bn_gs + l*48, bn_bs + l*48, N/16, N);
  }
  k_out<<<Nl,256,0,stream>>>(sbuf, out_ws, (float*)d_out);
}

// Round 6
// 501.515 us; speedup vs baseline: 1.4837x; 1.4837x over previous
//
#include <hip/hip_runtime.h>
#include <hip/hip_bf16.h>
#include <math.h>

#define I48 0.14433756729740643f  // 1/sqrt(48)
#define NKB 194                   // 6144 W rows + 64 bias rows, /32
#define KCH 4                     // kblks per LDS chunk (12 KiB fp16)
#define KSPL 6                    // K-split across blockIdx.y

typedef __attribute__((ext_vector_type(8))) _Float16 half8;
typedef __attribute__((ext_vector_type(4))) float f32x4;

__device__ __forceinline__ float silu_f(float x){ return x / (1.f + __expf(-x)); }

// ---------------- time embedding (1 block, 128 thr) ----------------
__global__ void k_temb(const float* __restrict__ t_in,
                       const float* __restrict__ w1, const float* __restrict__ b1,
                       const float* __restrict__ w2, const float* __restrict__ b2,
                       const float* __restrict__ g,  const float* __restrict__ b,
                       float* __restrict__ temb){
  __shared__ float emb[64], h1[128], red[128];
  __shared__ float s_mu, s_rs;
  int t = threadIdx.x;
  float tv = t_in[0];
  if (t < 64){
    int i = t & 31;
    float fr = __expf((float)i * (-9.210340371976184f/31.f));
    float a = tv * fr;
    emb[t] = (t < 32) ? sinf(a) : cosf(a);
  }
  __syncthreads();
  {
    float z = b1[t];
    for (int i=0;i<64;i++) z += emb[i]*w1[i*128+t];
    h1[t] = silu_f(z);
  }
  __syncthreads();
  float tp = 0.f;
  if (t < 64){
    tp = b2[t];
    for (int j=0;j<128;j++) tp += h1[j]*w2[j*64+t];
  }
  red[t] = (t<64)? tp : 0.f;
  __syncthreads();
  for (int st=64;st;st>>=1){ if(t<st) red[t]+=red[t+st]; __syncthreads(); }
  if (t==0) s_mu = red[0]/64.f;
  __syncthreads();
  float d = tp - s_mu;
  red[t] = (t<64)? d*d : 0.f;
  __syncthreads();
  for (int st=64;st;st>>=1){ if(t<st) red[t]+=red[t+st]; __syncthreads(); }
  if (t==0) s_rs = rsqrtf(red[0]/64.f + 1e-5f);
  __syncthreads();
  if (t<64) temb[t] = g[t]*(d*s_rs) + b[t];
}

// ------- node encoder fused with s0: x -> LN128 -> silu -> 48 -> sp_w -> emb_w*I48 -------
__global__ void k_encs0(const float* __restrict__ x, int in_dim,
                        const float* __restrict__ w1, const float* __restrict__ b1,
                        const float* __restrict__ g,  const float* __restrict__ bb,
                        const float* __restrict__ w2, const float* __restrict__ b2,
                        const float* __restrict__ spw, const float* __restrict__ spb,
                        const float* __restrict__ embw,
                        float* __restrict__ s, int row_off){
  __shared__ float sx[96], sh[128], red[128], vout[48], c48[48];
  __shared__ float s_mu, s_rs;
  int row = blockIdx.x, t = threadIdx.x;
  for (int i=t;i<in_dim;i+=128) sx[i] = x[(size_t)row*in_dim+i];
  __syncthreads();
  float z = b1[t];
  for (int i=0;i<in_dim;i++) z += sx[i]*w1[i*128+t];
  red[t]=z; __syncthreads();
  for (int st=64;st;st>>=1){ if(t<st) red[t]+=red[t+st]; __syncthreads(); }
  if(!t) s_mu = red[0]/128.f;
  __syncthreads();
  float d = z - s_mu;
  red[t]=d*d; __syncthreads();
  for (int st=64;st;st>>=1){ if(t<st) red[t]+=red[t+st]; __syncthreads(); }
  if(!t) s_rs = rsqrtf(red[0]/128.f+1e-5f);
  __syncthreads();
  float h = g[t]*(d*s_rs)+bb[t];
  sh[t] = silu_f(h);
  __syncthreads();
  if (t<48){
    float o = b2[t];
    for (int j=0;j<128;j++) o += sh[j]*w2[j*48+t];
    vout[t] = o;
  }
  __syncthreads();
  if (t<48){
    float c = spb[t];
    for (int i=0;i<48;i++) c += vout[i]*spw[i*48+t];
    c48[t] = c;
  }
  __syncthreads();
  if (t<48){
    float v = 0.f;
    for (int i=0;i<48;i++) v += c48[i]*embw[i*48+t];
    s[(size_t)(row_off+row)*48+t] = v*I48;
  }
}

// ---------------- per-edge: dist -> ef(32); also degree atomics ----------------
__global__ void k_edge(const float* __restrict__ lc, const float* __restrict__ pc,
                       const int* __restrict__ src, const int* __restrict__ dst,
                       const float* __restrict__ temb,
                       const float* __restrict__ w1, const float* __restrict__ b1,
                       const float* __restrict__ w2, const float* __restrict__ b2,
                       float* __restrict__ ef, float* __restrict__ degf,
                       int E, int Nl){
  __shared__ float sh_h[2][32];
  int t = threadIdx.x, sub = t>>5, j = t&31;
  int e = blockIdx.x*2 + sub;
  if (e < E){
    int s_ = src[e], d_ = dst[e];
    float vx = lc[(size_t)s_*3+0]-pc[(size_t)d_*6+0];
    float vy = lc[(size_t)s_*3+1]-pc[(size_t)d_*6+1];
    float vz = lc[(size_t)s_*3+2]-pc[(size_t)d_*6+2];
    float dist = sqrtf(vx*vx+vy*vy+vz*vz+1e-12f);
    float h = b1[j] + dist*w1[j];
    for (int a=0;a<64;a++) h += temb[a]*w1[(a+1)*32+j];
    sh_h[sub][j] = silu_f(h);
  }
  __syncthreads();
  if (e < E){
    float o = b2[j];
    for (int a=0;a<32;a++) o += sh_h[sub][a]*w2[a*32+j];
    ef[(size_t)e*32+j] = o;
    if (j==0) atomicAdd(&degf[Nl + dst[e]], 1.f);
  }
}

// ---------------- pack conv MLP weights into MFMA B-fragment order, fp16 ----------------
__global__ void k_packMLP(const float* __restrict__ w1, const float* __restrict__ w2,
                          _Float16* __restrict__ w1p, _Float16* __restrict__ w2p, int L){
  int tot1 = L*8*512;
  int tot2 = L*32*512;
  int total = tot1 + tot2;
  for (int idx = blockIdx.x*blockDim.x+threadIdx.x; idx < total; idx += gridDim.x*blockDim.x){
    if (idx < tot1){
      int j = idx & 7, lane = (idx>>3)&63, rest = idx>>9;
      int nt = rest & 7, l = rest >> 3;
      int k = (lane>>4)*8 + j, o = nt*16 + (lane&15);
      w1p[idx] = (_Float16)w1[((size_t)l*32 + k)*128 + o];
    } else {
      int i2 = idx - tot1;
      int j = i2 & 7, lane = (i2>>3)&63, rest = i2>>9;
      int nt = rest & 7, kb = (rest>>3)&3, l = rest >> 5;
      int k = kb*32 + (lane>>4)*8 + j, o = nt*16 + (lane&15);
      w2p[i2] = (_Float16)w2[((size_t)l*128 + k)*128 + o];
    }
  }
}

// ---------------- edge MLP via MFMA: 64 edges x 1 layer per block ----------------
__global__ __launch_bounds__(256) void k_mlp2(
    const float* __restrict__ ef,
    const _Float16* __restrict__ w1p, const float* __restrict__ b1a,
    const _Float16* __restrict__ w2p, const float* __restrict__ b2a,
    _Float16* __restrict__ m2h, int E){
  __shared__ __align__(16) _Float16 sef[64][40];
  __shared__ __align__(16) _Float16 shh[64][136];
  __shared__ float sb1[128], sb2[128];
  const int t = threadIdx.x, lane = t & 63, w = t >> 6;
  const int e0 = blockIdx.x * 64;
  const int l  = blockIdx.y;
  const _Float16* w1l = w1p + (size_t)l*4096;
  const _Float16* w2l = w2p + (size_t)l*16384;
  if (t < 128) sb1[t] = b1a[l*128 + t];
  else         sb2[t-128] = b2a[l*128 + (t-128)];
  {
    int row = t >> 2, g = t & 3;
    const float* p = ef + ((size_t)(e0+row))*32 + g*8;
    float4 p0 = *(const float4*)p, p1 = *(const float4*)(p+4);
    half8 hv;
    hv[0]=(_Float16)p0.x; hv[1]=(_Float16)p0.y; hv[2]=(_Float16)p0.z; hv[3]=(_Float16)p0.w;
    hv[4]=(_Float16)p1.x; hv[5]=(_Float16)p1.y; hv[6]=(_Float16)p1.z; hv[7]=(_Float16)p1.w;
    *(half8*)&sef[row][g*8] = hv;
  }
  __syncthreads();
  const int m = lane & 15, quad = lane >> 4;
  const int r = w*16 + m;
  half8 a1 = *(const half8*)&sef[r][quad*8];
  f32x4 acc1[8];
  #pragma unroll
  for (int nt=0; nt<8; nt++){
    half8 b = *(const half8*)(w1l + (nt*64 + lane)*8);
    f32x4 z = {0.f,0.f,0.f,0.f};
    acc1[nt] = __builtin_amdgcn_mfma_f32_16x16x32_f16(a1, b, z, 0,0,0);
  }
  #pragma unroll
  for (int nt=0; nt<8; nt++){
    float bv = sb1[nt*16 + m];
    #pragma unroll
    for (int rr=0; rr<4; rr++)
      shh[w*16 + quad*4 + rr][nt*16 + m] = (_Float16)silu_f(acc1[nt][rr] + bv);
  }
  __syncthreads();
  f32x4 acc2[8];
  #pragma unroll
  for (int nt=0;nt<8;nt++) acc2[nt] = (f32x4){0.f,0.f,0.f,0.f};
  #pragma unroll
  for (int kb=0; kb<4; kb++){
    half8 a2 = *(const half8*)&shh[r][kb*32 + quad*8];
    #pragma unroll
    for (int nt=0; nt<8; nt++){
      half8 b = *(const half8*)(w2l + ((size_t)(kb*8+nt)*64 + lane)*8);
      acc2[nt] = __builtin_amdgcn_mfma_f32_16x16x32_f16(a2, b, acc2[nt], 0,0,0);
    }
  }
  __syncthreads();
  #pragma unroll
  for (int nt=0; nt<8; nt++){
    float bv = sb2[nt*16 + m];
    #pragma unroll
    for (int rr=0; rr<4; rr++)
      shh[w*16 + quad*4 + rr][nt*16 + m] = (_Float16)silu_f(acc2[nt][rr] + bv);
  }
  __syncthreads();
  for (int q = t; q < 64*16; q += 256){
    int row = q >> 4, c = q & 15;
    half8 hv = *(const half8*)&shh[row][c*8];
    *(half8*)(m2h + ((size_t)l*E + e0 + row)*128 + c*8) = hv;
  }
}

// ---------------- pack W (+bias rows): READ-coalesced, scattered 2B writes ----------------
__global__ void k_packB2(const float* __restrict__ w3, const float* __restrict__ b3,
                         _Float16* __restrict__ wbh, int L){
  int tot1 = L*128*2304;
  int tot2 = L*64*48;
  int total = tot1 + tot2;
  for (int idx = blockIdx.x*blockDim.x+threadIdx.x; idx < total; idx += gridDim.x*blockDim.x){
    if (idx < tot1){
      int r = idx % 2304; int q = idx / 2304;
      int kk = q & 127;   int l = q >> 7;
      float v = w3[(size_t)(l*128+kk)*11520 + r];
      int i = r / 48, o = r - i*48;
      int kp = i*128 + kk;
      int kblk = kp >> 5, p = kp & 31;
      int lane = ((p>>3)<<4) + (o & 15);
      int j = p & 7;
      int nt = o >> 4;
      wbh[((((size_t)l*NKB + kblk)*3 + nt)*64 + lane)*8 + j] = (_Float16)v;
    } else {
      int i2 = idx - tot1;
      int o = i2 % 48; int q = i2 / 48;
      int ii = q & 63; int l = q >> 6;
      float v = (ii < 48) ? b3[(size_t)l*11520 + ii*48 + o] : 0.f;
      int kp = 6144 + ii;
      int kblk = kp >> 5, p = kp & 31;
      int lane = ((p>>3)<<4) + (o & 15);
      int j = p & 7;
      int nt = o >> 4;
      wbh[((((size_t)l*NKB + kblk)*3 + nt)*64 + lane)*8 + j] = (_Float16)v;
    }
  }
}

// ---------------- hot kernel: fp16 MFMA GEMM, 128 edges x K-range per block ----------------
__global__ __launch_bounds__(256) void k_msg4(
    const _Float16* __restrict__ m2h, const float* __restrict__ s,
    const _Float16* __restrict__ wbh,
    const int* __restrict__ src, const int* __restrict__ dst,
    float* __restrict__ Sacc, int Nl){
  __shared__ __align__(16) _Float16 sB[2][KCH*1536];   // 2 x 12 KiB
  __shared__ __align__(16) _Float16 sm2h[128][136];    // 34.8 KiB
  __shared__ __align__(16) _Float16 sseq[128][72];     // 18.4 KiB
  __shared__ int sdst[128];
  const int t = threadIdx.x, lane = t & 63, w = t >> 6;
  const int e0 = blockIdx.x * 128;
  const int by = blockIdx.y;
  const int kb0 = (NKB*by)/KSPL, kb1 = (NKB*(by+1))/KSPL;

  for (int q = t; q < 128*16; q += 256){
    int e = q >> 4, c = q & 15;
    float4 v = *(const float4*)(m2h + ((size_t)(e0+e))*128 + c*8);
    *(float4*)&sm2h[e][c*8] = v;
  }
  for (int q = t; q < 128*9; q += 256){
    int e = q/9, g = q - e*9;
    half8 hv = {};
    if (g < 6){
      const float* sp = s + (size_t)src[e0+e]*48 + g*8;
      float4 p0 = *(const float4*)sp, p1 = *(const float4*)(sp+4);
      hv[0]=(_Float16)p0.x; hv[1]=(_Float16)p0.y; hv[2]=(_Float16)p0.z; hv[3]=(_Float16)p0.w;
      hv[4]=(_Float16)p1.x; hv[5]=(_Float16)p1.y; hv[6]=(_Float16)p1.z; hv[7]=(_Float16)p1.w;
    }
    *(half8*)&sseq[e][g*8] = hv;
  }
  if (t < 128) sdst[t] = dst[e0+t];

  auto stage = [&](int c){
    int kbase = kb0 + c*KCH;
    int nk = kb1 - kbase; if (nk > KCH) nk = KCH;
    int bytes = nk*3072;
    const char* g = (const char*)wbh + (size_t)kbase*3072;
    char* lb = (char*)sB[c&1];
    for (int off = w*1024; off < bytes; off += 4096){
      __builtin_amdgcn_global_load_lds(
        (const __attribute__((address_space(1))) void*)(g + off + (size_t)lane*16),
        (__attribute__((address_space(3))) void*)(lb + off), 16, 0, 0);
    }
  };
  stage(0);

  const int m = lane & 15, quad = lane >> 4;
  const int r0 = w*32 + m, r1 = r0 + 16;
  f32x4 acc00={0.f,0.f,0.f,0.f}, acc01={0.f,0.f,0.f,0.f}, acc02={0.f,0.f,0.f,0.f};
  f32x4 acc10={0.f,0.f,0.f,0.f}, acc11={0.f,0.f,0.f,0.f}, acc12={0.f,0.f,0.f,0.f};

  const int nch = (kb1-kb0+KCH-1)/KCH;
  for (int c = 0; c < nch; c++){
    __syncthreads();
    if (c+1 < nch) stage(c+1);
    int kbase = kb0 + c*KCH;
    int kbn = kb1 - kbase; if (kbn > KCH) kbn = KCH;
    const _Float16* bb = sB[c&1];
    for (int kk = 0; kk < kbn; kk++){
      int kblk = kbase + kk;
      half8 a0, a1;
      if (kblk < 192){
        int i = kblk >> 2;
        int base = ((kblk & 3) << 5) + quad*8;
        _Float16 sv0 = sseq[r0][i], sv1 = sseq[r1][i];
        half8 m0 = *(const half8*)&sm2h[r0][base];
        half8 m1 = *(const half8*)&sm2h[r1][base];
        half8 s0v = {sv0,sv0,sv0,sv0,sv0,sv0,sv0,sv0};
        half8 s1v = {sv1,sv1,sv1,sv1,sv1,sv1,sv1,sv1};
        a0 = m0 * s0v;
        a1 = m1 * s1v;
      } else {
        int ib = ((kblk-192) << 5) + quad*8;
        a0 = *(const half8*)&sseq[r0][ib];
        a1 = *(const half8*)&sseq[r1][ib];
      }
      const _Float16* bk = bb + kk*1536 + lane*8;
      half8 b0 = *(const half8*)(bk);
      half8 b1 = *(const half8*)(bk + 512);
      half8 b2 = *(const half8*)(bk + 1024);
      acc00 = __builtin_amdgcn_mfma_f32_16x16x32_f16(a0, b0, acc00, 0, 0, 0);
      acc01 = __builtin_amdgcn_mfma_f32_16x16x32_f16(a0, b1, acc01, 0, 0, 0);
      acc02 = __builtin_amdgcn_mfma_f32_16x16x32_f16(a0, b2, acc02, 0, 0, 0);
      acc10 = __builtin_amdgcn_mfma_f32_16x16x32_f16(a1, b0, acc10, 0, 0, 0);
      acc11 = __builtin_amdgcn_mfma_f32_16x16x32_f16(a1, b1, acc11, 0, 0, 0);
      acc12 = __builtin_amdgcn_mfma_f32_16x16x32_f16(a1, b2, acc12, 0, 0, 0);
    }
  }
  #pragma unroll
  for (int r = 0; r < 4; r++){
    int el0 = w*32 + quad*4 + r;
    int el1 = el0 + 16;
    float* p0 = Sacc + (size_t)(Nl + sdst[el0])*48 + m;
    float* p1 = Sacc + (size_t)(Nl + sdst[el1])*48 + m;
    atomicAdd(p0 +  0, acc00[r]*I48);
    atomicAdd(p0 + 16, acc01[r]*I48);
    atomicAdd(p0 + 32, acc02[r]*I48);
    atomicAdd(p1 +  0, acc10[r]*I48);
    atomicAdd(p1 + 16, acc11[r]*I48);
    atomicAdd(p1 + 32, acc12[r]*I48);
  }
}

// ---------------- node update: a_s = Sacc/deg + s@si_ws*I48 ; BN partials ----------------
__global__ __launch_bounds__(256) void k_node(const float* __restrict__ Sacc,
                       const float* __restrict__ degf,
                       const float* __restrict__ s, const float* __restrict__ siw,
                       float* __restrict__ a_s, float* __restrict__ bnpart, int N){
  __shared__ float sh_s[16][48];
  __shared__ float sw[2304];
  __shared__ float csum[48], csq[48];
  int t = threadIdx.x;
  int n0 = blockIdx.x*16;
  for (int q=t;q<2304;q+=256) sw[q] = siw[q];
  for (int q=t;q<768;q+=256){
    int nl=q/48, i=q-nl*48;
    sh_s[nl][i] = s[(size_t)(n0+nl)*48+i];
  }
  if (t<48){ csum[t]=0.f; csq[t]=0.f; }
  __syncthreads();
  int nl = t>>4;
  int ob = (t&15)*3;
  int n = n0+nl;
  float dg = degf[n]; if (dg < 1.f) dg = 1.f;
  float inv = 1.f/dg;
  #pragma unroll
  for (int j=0;j<3;j++){
    int o = ob+j;
    float acc = 0.f;
    for (int i=0;i<48;i++) acc += sh_s[nl][i]*sw[i*48+o];
    float a = Sacc[(size_t)n*48+o]*inv + acc*I48;
    a_s[(size_t)n*48+o] = a;
    atomicAdd(&csum[o], a);
    atomicAdd(&csq[o], a*a);
  }
  __syncthreads();
  if (t<96) bnpart[(size_t)blockIdx.x*96 + t] = (t<48) ? csum[t] : csq[t-48];
}

// ---------------- BN finalize: 1 block, 768 thr, 4 loads in flight ----------------
__global__ void k_bnfin2(const float* __restrict__ bnpart,
                         const float* __restrict__ g, const float* __restrict__ b,
                         float* __restrict__ kscale, float* __restrict__ kbias,
                         int nblk, int N){
  __shared__ float red[8][96];
  __shared__ float tot[96];
  int t = threadIdx.x;           // 768 threads
  int gg = t/96, o = t - gg*96;
  float a0=0.f,a1=0.f,a2=0.f,a3=0.f;
  int bk = gg;
  for (; bk+24 < nblk; bk += 32){
    a0 += bnpart[(size_t)bk*96 + o];
    a1 += bnpart[(size_t)(bk+8)*96 + o];
    a2 += bnpart[(size_t)(bk+16)*96 + o];
    a3 += bnpart[(size_t)(bk+24)*96 + o];
  }
  for (; bk < nblk; bk += 8) a0 += bnpart[(size_t)bk*96 + o];
  red[gg][o] = (a0+a1)+(a2+a3);
  __syncthreads();
  if (t<96){
    float s2 = 0.f;
    #pragma unroll
    for (int k=0;k<8;k++) s2 += red[k][t];
    tot[t] = s2;
  }
  __syncthreads();
  if (t<48){
    float mu  = tot[t]/(float)N;
    float var = tot[48+t]/(float)N - mu*mu;
    float r = rsqrtf(var + 1e-5f);
    float sc = g[t]*r;
    kscale[t] = sc;
    kbias[t]  = b[t] - mu*sc;
  }
}

// s += a_s*scale + bias ; also zero Sacc for next layer
__global__ void k_supd(float* __restrict__ s, float* __restrict__ Sacc,
                       const float* __restrict__ a_s,
                       const float* __restrict__ kscale, const float* __restrict__ kbias,
                       int total){
  int idx = blockIdx.x*blockDim.x+threadIdx.x;
  if (idx < total){
    int o = idx % 48;
    s[idx] += a_s[idx]*kscale[o] + kbias[o];
    Sacc[idx] = 0.f;
  }
}

// ---------------- output ----------------
__global__ void k_out(const float* __restrict__ s, const float* __restrict__ ows,
                      float* __restrict__ out){
  __shared__ float sh_s[48];
  int n = blockIdx.x, t = threadIdx.x;
  if (t<48) sh_s[t] = s[(size_t)n*48+t];
  __syncthreads();
  float acc = 0.f;
  for (int i=0;i<48;i++) acc += sh_s[i]*ows[i*256+t];
  out[(size_t)n*259 + 3 + t] = acc*I48;
  if (t<3) out[(size_t)n*259 + t] = 0.f;
}

extern "C" void kernel_launch(void* const* d_in, const int* in_sizes, int n_in,
                              void* d_out, int out_size, void* d_ws, size_t ws_size,
                              hipStream_t stream){
  const float* protein_coords   = (const float*)d_in[0];
  const float* protein_features = (const float*)d_in[1];
  const float* ligand_coords    = (const float*)d_in[2];
  const float* ligand_features  = (const float*)d_in[3];
  const float* t_in    = (const float*)d_in[4];
  const float* te_w1   = (const float*)d_in[5];
  const float* te_b1   = (const float*)d_in[6];
  const float* te_w2   = (const float*)d_in[7];
  const float* te_b2   = (const float*)d_in[8];
  const float* te_ln_g = (const float*)d_in[9];
  const float* te_ln_b = (const float*)d_in[10];
  const float* pe_w1   = (const float*)d_in[11];
  const float* pe_b1   = (const float*)d_in[12];
  const float* pe_ln_g = (const float*)d_in[13];
  const float* pe_ln_b = (const float*)d_in[14];
  const float* pe_w2   = (const float*)d_in[15];
  const float* pe_b2   = (const float*)d_in[16];
  const float* le_w1   = (const float*)d_in[17];
  const float* le_b1   = (const float*)d_in[18];
  const float* le_ln_g = (const float*)d_in[19];
  const float* le_ln_b = (const float*)d_in[20];
  const float* le_w2   = (const float*)d_in[21];
  const float* le_b2   = (const float*)d_in[22];
  const float* sp_w    = (const float*)d_in[23];
  const float* sp_b    = (const float*)d_in[24];
  const float* emb_w   = (const float*)d_in[25];
  const float* ee_w1   = (const float*)d_in[26];
  const float* ee_b1   = (const float*)d_in[27];
  const float* ee_w2   = (const float*)d_in[28];
  const float* ee_b2   = (const float*)d_in[29];
  const float* conv_w1 = (const float*)d_in[30];
  const float* conv_b1 = (const float*)d_in[31];
  const float* conv_w2 = (const float*)d_in[32];
  const float* conv_b2 = (const float*)d_in[33];
  const float* conv_w3 = (const float*)d_in[34];
  const float* conv_b3 = (const float*)d_in[35];
  const float* bn_gs   = (const float*)d_in[36];
  const float* bn_bs   = (const float*)d_in[37];
  const float* si_ws   = (const float*)d_in[40];
  const float* out_ws  = (const float*)d_in[43];
  const int* edge_src  = (const int*)d_in[45];
  const int* edge_dst  = (const int*)d_in[46];

  int Np = in_sizes[0]/6;
  int Nl = in_sizes[2]/3;
  int E  = in_sizes[45];
  int N  = Nl+Np;
  int L  = in_sizes[36]/48;

  float* W = (float*)d_ws;
  size_t off = 0;
  auto alloc = [&](size_t n)->float*{ float* p = W+off; off += (n+63)&~(size_t)63; return p; };
  float* temb  = alloc(64);
  float* sbuf  = alloc((size_t)N*48);
  float* ef    = alloc((size_t)E*32);
  float* degf  = alloc(N);
  float* Sacc  = alloc((size_t)N*48);
  float* a_s   = alloc((size_t)N*48);
  float* bnpart= alloc((size_t)(N/16)*96);
  float* kscale= alloc(64);
  float* kbias = alloc(64);
  _Float16* m2h = (_Float16*)alloc((size_t)L*E*128/2 + 64);
  _Float16* wbh = (_Float16*)alloc((size_t)L*NKB*1536/2 + 64);
  _Float16* w1p = (_Float16*)alloc((size_t)L*4096/2 + 64);
  _Float16* w2p = (_Float16*)alloc((size_t)L*16384/2 + 64);

  hipMemsetAsync(degf, 0, (size_t)N*sizeof(float), stream);
  hipMemsetAsync(Sacc, 0, (size_t)N*48*sizeof(float), stream);
  k_packB2<<<2048,256,0,stream>>>(conv_w3, conv_b3, wbh, L);
  k_packMLP<<<480,256,0,stream>>>(conv_w1, conv_w2, w1p, w2p, L);
  k_temb<<<1,128,0,stream>>>(t_in, te_w1, te_b1, te_w2, te_b2, te_ln_g, te_ln_b, temb);
  k_encs0<<<Np,128,0,stream>>>(protein_features, 96, pe_w1, pe_b1, pe_ln_g, pe_ln_b,
                               pe_w2, pe_b2, sp_w, sp_b, emb_w, sbuf, Nl);
  k_encs0<<<Nl,128,0,stream>>>(ligand_features, 52, le_w1, le_b1, le_ln_g, le_ln_b,
                               le_w2, le_b2, sp_w, sp_b, emb_w, sbuf, 0);
  k_edge<<<(E+1)/2,64,0,stream>>>(ligand_coords, protein_coords, edge_src, edge_dst, temb,
                                  ee_w1, ee_b1, ee_w2, ee_b2, ef, degf, E, Nl);
  dim3 mlpg(E/64, L);
  k_mlp2<<<mlpg,256,0,stream>>>(ef, w1p, conv_b1, w2p, conv_b2, m2h, E);

  dim3 mgrid(E/128, KSPL);
  for (int l=0;l<L;l++){
    k_msg4<<<mgrid,256,0,stream>>>(m2h + (size_t)l*E*128, sbuf, wbh + (size_t)l*NKB*1536,
                                   edge_src, edge_dst, Sacc, Nl);
    k_node<<<N/16,256,0,stream>>>(Sacc, degf, sbuf, si_ws + (size_t)l*2304, a_s, bnpart, N);
    k_bnfin2<<<1,768,0,stream>>>(bnpart, bn_gs + l*48, bn_bs + l*48, kscale, kbias, N/16, N);
    k_supd<<<((size_t)N*48+255)/256,256,0,stream>>>(sbuf, Sacc, a_s, kscale, kbias, N*48);
  }
  k_out<<<Nl,256,0,stream>>>(sbuf, out_ws, (float*)d_out);
}

// Round 7
// 482.501 us; speedup vs baseline: 1.5421x; 1.0394x over previous
//
#include <hip/hip_runtime.h>
#include <hip/hip_bf16.h>
#include <math.h>

#define I48 0.14433756729740643f  // 1/sqrt(48)
#define NKB 194                   // 6144 W rows + 64 bias rows, /32
#define KCH 4                     // kblks per LDS chunk (12 KiB fp16)
#define KSPL 6                    // K-split across blockIdx.y (boundaries 32-aligned)

typedef __attribute__((ext_vector_type(8))) _Float16 half8;
typedef __attribute__((ext_vector_type(4))) float f32x4;

__device__ __forceinline__ float silu_f(float x){ return x / (1.f + __expf(-x)); }

// ---------------- time embedding (1 block, 128 thr) ----------------
__global__ void k_temb(const float* __restrict__ t_in,
                       const float* __restrict__ w1, const float* __restrict__ b1,
                       const float* __restrict__ w2, const float* __restrict__ b2,
                       const float* __restrict__ g,  const float* __restrict__ b,
                       float* __restrict__ temb){
  __shared__ float emb[64], h1[128], red[128];
  __shared__ float s_mu, s_rs;
  int t = threadIdx.x;
  float tv = t_in[0];
  if (t < 64){
    int i = t & 31;
    float fr = __expf((float)i * (-9.210340371976184f/31.f));
    float a = tv * fr;
    emb[t] = (t < 32) ? sinf(a) : cosf(a);
  }
  __syncthreads();
  {
    float z = b1[t];
    for (int i=0;i<64;i++) z += emb[i]*w1[i*128+t];
    h1[t] = silu_f(z);
  }
  __syncthreads();
  float tp = 0.f;
  if (t < 64){
    tp = b2[t];
    for (int j=0;j<128;j++) tp += h1[j]*w2[j*64+t];
  }
  red[t] = (t<64)? tp : 0.f;
  __syncthreads();
  for (int st=64;st;st>>=1){ if(t<st) red[t]+=red[t+st]; __syncthreads(); }
  if (t==0) s_mu = red[0]/64.f;
  __syncthreads();
  float d = tp - s_mu;
  red[t] = (t<64)? d*d : 0.f;
  __syncthreads();
  for (int st=64;st;st>>=1){ if(t<st) red[t]+=red[t+st]; __syncthreads(); }
  if (t==0) s_rs = rsqrtf(red[0]/64.f + 1e-5f);
  __syncthreads();
  if (t<64) temb[t] = g[t]*(d*s_rs) + b[t];
}

// ------- node encoder fused with s0: x -> LN128 -> silu -> 48 -> sp_w -> emb_w*I48 -------
__global__ void k_encs0(const float* __restrict__ x, int in_dim,
                        const float* __restrict__ w1, const float* __restrict__ b1,
                        const float* __restrict__ g,  const float* __restrict__ bb,
                        const float* __restrict__ w2, const float* __restrict__ b2,
                        const float* __restrict__ spw, const float* __restrict__ spb,
                        const float* __restrict__ embw,
                        float* __restrict__ s, int row_off){
  __shared__ float sx[96], sh[128], red[128], vout[48], c48[48];
  __shared__ float s_mu, s_rs;
  int row = blockIdx.x, t = threadIdx.x;
  for (int i=t;i<in_dim;i+=128) sx[i] = x[(size_t)row*in_dim+i];
  __syncthreads();
  float z = b1[t];
  for (int i=0;i<in_dim;i++) z += sx[i]*w1[i*128+t];
  red[t]=z; __syncthreads();
  for (int st=64;st;st>>=1){ if(t<st) red[t]+=red[t+st]; __syncthreads(); }
  if(!t) s_mu = red[0]/128.f;
  __syncthreads();
  float d = z - s_mu;
  red[t]=d*d; __syncthreads();
  for (int st=64;st;st>>=1){ if(t<st) red[t]+=red[t+st]; __syncthreads(); }
  if(!t) s_rs = rsqrtf(red[0]/128.f+1e-5f);
  __syncthreads();
  float h = g[t]*(d*s_rs)+bb[t];
  sh[t] = silu_f(h);
  __syncthreads();
  if (t<48){
    float o = b2[t];
    for (int j=0;j<128;j++) o += sh[j]*w2[j*48+t];
    vout[t] = o;
  }
  __syncthreads();
  if (t<48){
    float c = spb[t];
    for (int i=0;i<48;i++) c += vout[i]*spw[i*48+t];
    c48[t] = c;
  }
  __syncthreads();
  if (t<48){
    float v = 0.f;
    for (int i=0;i<48;i++) v += c48[i]*embw[i*48+t];
    s[(size_t)(row_off+row)*48+t] = v*I48;
  }
}

// ---------------- per-edge: dist -> ef(32); also degree atomics ----------------
__global__ void k_edge(const float* __restrict__ lc, const float* __restrict__ pc,
                       const int* __restrict__ src, const int* __restrict__ dst,
                       const float* __restrict__ temb,
                       const float* __restrict__ w1, const float* __restrict__ b1,
                       const float* __restrict__ w2, const float* __restrict__ b2,
                       float* __restrict__ ef, float* __restrict__ degf,
                       int E, int Nl){
  __shared__ float sh_h[2][32];
  int t = threadIdx.x, sub = t>>5, j = t&31;
  int e = blockIdx.x*2 + sub;
  if (e < E){
    int s_ = src[e], d_ = dst[e];
    float vx = lc[(size_t)s_*3+0]-pc[(size_t)d_*6+0];
    float vy = lc[(size_t)s_*3+1]-pc[(size_t)d_*6+1];
    float vz = lc[(size_t)s_*3+2]-pc[(size_t)d_*6+2];
    float dist = sqrtf(vx*vx+vy*vy+vz*vz+1e-12f);
    float h = b1[j] + dist*w1[j];
    for (int a=0;a<64;a++) h += temb[a]*w1[(a+1)*32+j];
    sh_h[sub][j] = silu_f(h);
  }
  __syncthreads();
  if (e < E){
    float o = b2[j];
    for (int a=0;a<32;a++) o += sh_h[sub][a]*w2[a*32+j];
    ef[(size_t)e*32+j] = o;
    if (j==0) atomicAdd(&degf[Nl + dst[e]], 1.f);
  }
}

// ---------------- pack conv MLP weights into MFMA B-fragment order, fp16 ----------------
__global__ void k_packMLP(const float* __restrict__ w1, const float* __restrict__ w2,
                          _Float16* __restrict__ w1p, _Float16* __restrict__ w2p, int L){
  int tot1 = L*8*512;
  int tot2 = L*32*512;
  int total = tot1 + tot2;
  for (int idx = blockIdx.x*blockDim.x+threadIdx.x; idx < total; idx += gridDim.x*blockDim.x){
    if (idx < tot1){
      int j = idx & 7, lane = (idx>>3)&63, rest = idx>>9;
      int nt = rest & 7, l = rest >> 3;
      int k = (lane>>4)*8 + j, o = nt*16 + (lane&15);
      w1p[idx] = (_Float16)w1[((size_t)l*32 + k)*128 + o];
    } else {
      int i2 = idx - tot1;
      int j = i2 & 7, lane = (i2>>3)&63, rest = i2>>9;
      int nt = rest & 7, kb = (rest>>3)&3, l = rest >> 5;
      int k = kb*32 + (lane>>4)*8 + j, o = nt*16 + (lane&15);
      w2p[i2] = (_Float16)w2[((size_t)l*128 + k)*128 + o];
    }
  }
}

// ---------------- edge MLP via MFMA: 64 edges x 1 layer per block ----------------
__global__ __launch_bounds__(256) void k_mlp2(
    const float* __restrict__ ef,
    const _Float16* __restrict__ w1p, const float* __restrict__ b1a,
    const _Float16* __restrict__ w2p, const float* __restrict__ b2a,
    _Float16* __restrict__ m2h, int E){
  __shared__ __align__(16) _Float16 sef[64][40];
  __shared__ __align__(16) _Float16 shh[64][136];
  __shared__ float sb1[128], sb2[128];
  const int t = threadIdx.x, lane = t & 63, w = t >> 6;
  const int e0 = blockIdx.x * 64;
  const int l  = blockIdx.y;
  const _Float16* w1l = w1p + (size_t)l*4096;
  const _Float16* w2l = w2p + (size_t)l*16384;
  if (t < 128) sb1[t] = b1a[l*128 + t];
  else         sb2[t-128] = b2a[l*128 + (t-128)];
  {
    int row = t >> 2, g = t & 3;
    const float* p = ef + ((size_t)(e0+row))*32 + g*8;
    float4 p0 = *(const float4*)p, p1 = *(const float4*)(p+4);
    half8 hv;
    hv[0]=(_Float16)p0.x; hv[1]=(_Float16)p0.y; hv[2]=(_Float16)p0.z; hv[3]=(_Float16)p0.w;
    hv[4]=(_Float16)p1.x; hv[5]=(_Float16)p1.y; hv[6]=(_Float16)p1.z; hv[7]=(_Float16)p1.w;
    *(half8*)&sef[row][g*8] = hv;
  }
  __syncthreads();
  const int m = lane & 15, quad = lane >> 4;
  const int r = w*16 + m;
  half8 a1 = *(const half8*)&sef[r][quad*8];
  f32x4 acc1[8];
  #pragma unroll
  for (int nt=0; nt<8; nt++){
    half8 b = *(const half8*)(w1l + (nt*64 + lane)*8);
    f32x4 z = {0.f,0.f,0.f,0.f};
    acc1[nt] = __builtin_amdgcn_mfma_f32_16x16x32_f16(a1, b, z, 0,0,0);
  }
  #pragma unroll
  for (int nt=0; nt<8; nt++){
    float bv = sb1[nt*16 + m];
    #pragma unroll
    for (int rr=0; rr<4; rr++)
      shh[w*16 + quad*4 + rr][nt*16 + m] = (_Float16)silu_f(acc1[nt][rr] + bv);
  }
  __syncthreads();
  f32x4 acc2[8];
  #pragma unroll
  for (int nt=0;nt<8;nt++) acc2[nt] = (f32x4){0.f,0.f,0.f,0.f};
  #pragma unroll
  for (int kb=0; kb<4; kb++){
    half8 a2 = *(const half8*)&shh[r][kb*32 + quad*8];
    #pragma unroll
    for (int nt=0; nt<8; nt++){
      half8 b = *(const half8*)(w2l + ((size_t)(kb*8+nt)*64 + lane)*8);
      acc2[nt] = __builtin_amdgcn_mfma_f32_16x16x32_f16(a2, b, acc2[nt], 0,0,0);
    }
  }
  __syncthreads();
  #pragma unroll
  for (int nt=0; nt<8; nt++){
    float bv = sb2[nt*16 + m];
    #pragma unroll
    for (int rr=0; rr<4; rr++)
      shh[w*16 + quad*4 + rr][nt*16 + m] = (_Float16)silu_f(acc2[nt][rr] + bv);
  }
  __syncthreads();
  for (int q = t; q < 64*16; q += 256){
    int row = q >> 4, c = q & 15;
    half8 hv = *(const half8*)&shh[row][c*8];
    *(half8*)(m2h + ((size_t)l*E + e0 + row)*128 + c*8) = hv;
  }
}

// ---------------- pack W (+bias rows): READ-coalesced, scattered 2B writes ----------------
__global__ void k_packB2(const float* __restrict__ w3, const float* __restrict__ b3,
                         _Float16* __restrict__ wbh, int L){
  int tot1 = L*128*2304;
  int tot2 = L*64*48;
  int total = tot1 + tot2;
  for (int idx = blockIdx.x*blockDim.x+threadIdx.x; idx < total; idx += gridDim.x*blockDim.x){
    if (idx < tot1){
      int r = idx % 2304; int q = idx / 2304;
      int kk = q & 127;   int l = q >> 7;
      float v = w3[(size_t)(l*128+kk)*11520 + r];
      int i = r / 48, o = r - i*48;
      int kp = i*128 + kk;
      int kblk = kp >> 5, p = kp & 31;
      int lane = ((p>>3)<<4) + (o & 15);
      int j = p & 7;
      int nt = o >> 4;
      wbh[((((size_t)l*NKB + kblk)*3 + nt)*64 + lane)*8 + j] = (_Float16)v;
    } else {
      int i2 = idx - tot1;
      int o = i2 % 48; int q = i2 / 48;
      int ii = q & 63; int l = q >> 6;
      float v = (ii < 48) ? b3[(size_t)l*11520 + ii*48 + o] : 0.f;
      int kp = 6144 + ii;
      int kblk = kp >> 5, p = kp & 31;
      int lane = ((p>>3)<<4) + (o & 15);
      int j = p & 7;
      int nt = o >> 4;
      wbh[((((size_t)l*NKB + kblk)*3 + nt)*64 + lane)*8 + j] = (_Float16)v;
    }
  }
}

// ---------------- hot kernel v5: A-side m2 held in registers; LDS only for B ----------------
// 128 edges x K-range per block. K-split boundaries 32-aligned so every full chunk
// has kbase%4==0 -> (kblk&3)==kk statically, and sv (=se[i]) is loaded once/chunk.
__global__ __launch_bounds__(256) void k_msg5(
    const _Float16* __restrict__ m2h, const float* __restrict__ s,
    const _Float16* __restrict__ wbh,
    const int* __restrict__ src, const int* __restrict__ dst,
    float* __restrict__ Sacc, int Nl){
  __shared__ __align__(16) _Float16 sB[2][KCH*1536];   // 2 x 12 KiB
  __shared__ __align__(16) _Float16 sseq[128][72];     // 18.4 KiB (se, zero-padded)
  __shared__ int sdst[128];
  const int t = threadIdx.x, lane = t & 63, w = t >> 6;
  const int e0 = blockIdx.x * 128;
  const int by = blockIdx.y;
  const int kb0 = by*32;
  const int kb1 = (by==KSPL-1) ? NKB : kb0+32;

  // stage se as fp16 rows (48 vals + zero pad)
  for (int q = t; q < 128*9; q += 256){
    int e = q/9, g = q - e*9;
    half8 hv = {};
    if (g < 6){
      const float* sp = s + (size_t)src[e0+e]*48 + g*8;
      float4 p0 = *(const float4*)sp, p1 = *(const float4*)(sp+4);
      hv[0]=(_Float16)p0.x; hv[1]=(_Float16)p0.y; hv[2]=(_Float16)p0.z; hv[3]=(_Float16)p0.w;
      hv[4]=(_Float16)p1.x; hv[5]=(_Float16)p1.y; hv[6]=(_Float16)p1.z; hv[7]=(_Float16)p1.w;
    }
    *(half8*)&sseq[e][g*8] = hv;
  }
  if (t < 128) sdst[t] = dst[e0+t];

  const int m = lane & 15, quad = lane >> 4;
  const int r0 = w*32 + m, r1 = r0 + 16;

  // A-side m2 fragments: each lane needs only slices [sub*32 + quad*8 .. +8]
  // of its two rows -> 4 half8 per row, loaded once from global (L2-hot).
  half8 f0[4], f1[4];
  {
    const _Float16* base0 = m2h + (size_t)(e0+r0)*128 + quad*8;
    const _Float16* base1 = m2h + (size_t)(e0+r1)*128 + quad*8;
    #pragma unroll
    for (int sub=0; sub<4; sub++){
      f0[sub] = *(const half8*)(base0 + sub*32);
      f1[sub] = *(const half8*)(base1 + sub*32);
    }
  }

  auto stage = [&](int c){
    int kbase = kb0 + c*KCH;
    int nk = kb1 - kbase; if (nk > KCH) nk = KCH;
    int bytes = nk*3072;
    const char* g = (const char*)wbh + (size_t)kbase*3072;
    char* lb = (char*)sB[c&1];
    for (int off = w*1024; off < bytes; off += 4096){
      __builtin_amdgcn_global_load_lds(
        (const __attribute__((address_space(1))) void*)(g + off + (size_t)lane*16),
        (__attribute__((address_space(3))) void*)(lb + off), 16, 0, 0);
    }
  };
  stage(0);

  f32x4 acc00={0.f,0.f,0.f,0.f}, acc01={0.f,0.f,0.f,0.f}, acc02={0.f,0.f,0.f,0.f};
  f32x4 acc10={0.f,0.f,0.f,0.f}, acc11={0.f,0.f,0.f,0.f}, acc12={0.f,0.f,0.f,0.f};

  const int nch = (kb1-kb0+KCH-1)/KCH;
  for (int c = 0; c < nch; c++){
    __syncthreads();              // drains stage(c)
    if (c+1 < nch) stage(c+1);    // prefetch next chunk into other buffer
    int kbase = kb0 + c*KCH;
    int kbn = kb1 - kbase; if (kbn > KCH) kbn = KCH;
    const _Float16* bb = sB[c&1];
    if (kbn == KCH && kbase < 192){
      int i = kbase >> 2;         // constant for whole chunk (kbase%4==0)
      _Float16 sv0 = sseq[r0][i], sv1 = sseq[r1][i];
      half8 s0v = {sv0,sv0,sv0,sv0,sv0,sv0,sv0,sv0};
      half8 s1v = {sv1,sv1,sv1,sv1,sv1,sv1,sv1,sv1};
      #pragma unroll
      for (int kk = 0; kk < KCH; kk++){
        half8 a0 = f0[kk] * s0v;  // v_pk_mul_f16 x4
        half8 a1 = f1[kk] * s1v;
        const _Float16* bk = bb + kk*1536 + lane*8;
        half8 b0 = *(const half8*)(bk);
        half8 b1 = *(const half8*)(bk + 512);
        half8 b2 = *(const half8*)(bk + 1024);
        acc00 = __builtin_amdgcn_mfma_f32_16x16x32_f16(a0, b0, acc00, 0, 0, 0);
        acc01 = __builtin_amdgcn_mfma_f32_16x16x32_f16(a0, b1, acc01, 0, 0, 0);
        acc02 = __builtin_amdgcn_mfma_f32_16x16x32_f16(a0, b2, acc02, 0, 0, 0);
        acc10 = __builtin_amdgcn_mfma_f32_16x16x32_f16(a1, b0, acc10, 0, 0, 0);
        acc11 = __builtin_amdgcn_mfma_f32_16x16x32_f16(a1, b1, acc11, 0, 0, 0);
        acc12 = __builtin_amdgcn_mfma_f32_16x16x32_f16(a1, b2, acc12, 0, 0, 0);
      }
    } else {
      // tail: bias rows (kblk 192,193): A = se (zero-padded)
      for (int kk = 0; kk < kbn; kk++){
        int kblk = kbase + kk;
        int ib = ((kblk-192) << 5) + quad*8;
        half8 a0 = *(const half8*)&sseq[r0][ib];
        half8 a1 = *(const half8*)&sseq[r1][ib];
        const _Float16* bk = bb + kk*1536 + lane*8;
        half8 b0 = *(const half8*)(bk);
        half8 b1 = *(const half8*)(bk + 512);
        half8 b2 = *(const half8*)(bk + 1024);
        acc00 = __builtin_amdgcn_mfma_f32_16x16x32_f16(a0, b0, acc00, 0, 0, 0);
        acc01 = __builtin_amdgcn_mfma_f32_16x16x32_f16(a0, b1, acc01, 0, 0, 0);
        acc02 = __builtin_amdgcn_mfma_f32_16x16x32_f16(a0, b2, acc02, 0, 0, 0);
        acc10 = __builtin_amdgcn_mfma_f32_16x16x32_f16(a1, b0, acc10, 0, 0, 0);
        acc11 = __builtin_amdgcn_mfma_f32_16x16x32_f16(a1, b1, acc11, 0, 0, 0);
        acc12 = __builtin_amdgcn_mfma_f32_16x16x32_f16(a1, b2, acc12, 0, 0, 0);
      }
    }
  }
  #pragma unroll
  for (int r = 0; r < 4; r++){
    int el0 = w*32 + quad*4 + r;
    int el1 = el0 + 16;
    float* p0 = Sacc + (size_t)(Nl + sdst[el0])*48 + m;
    float* p1 = Sacc + (size_t)(Nl + sdst[el1])*48 + m;
    atomicAdd(p0 +  0, acc00[r]*I48);
    atomicAdd(p0 + 16, acc01[r]*I48);
    atomicAdd(p0 + 32, acc02[r]*I48);
    atomicAdd(p1 +  0, acc10[r]*I48);
    atomicAdd(p1 + 16, acc11[r]*I48);
    atomicAdd(p1 + 32, acc12[r]*I48);
  }
}

// ---------------- node update: a_s = Sacc/deg + s@si_ws*I48 ; BN partials ----------------
__global__ __launch_bounds__(256) void k_node(const float* __restrict__ Sacc,
                       const float* __restrict__ degf,
                       const float* __restrict__ s, const float* __restrict__ siw,
                       float* __restrict__ a_s, float* __restrict__ bnpart, int N){
  __shared__ float sh_s[16][48];
  __shared__ float sw[2304];
  __shared__ float csum[48], csq[48];
  int t = threadIdx.x;
  int n0 = blockIdx.x*16;
  for (int q=t;q<2304;q+=256) sw[q] = siw[q];
  for (int q=t;q<768;q+=256){
    int nl=q/48, i=q-nl*48;
    sh_s[nl][i] = s[(size_t)(n0+nl)*48+i];
  }
  if (t<48){ csum[t]=0.f; csq[t]=0.f; }
  __syncthreads();
  int nl = t>>4;
  int ob = (t&15)*3;
  int n = n0+nl;
  float dg = degf[n]; if (dg < 1.f) dg = 1.f;
  float inv = 1.f/dg;
  #pragma unroll
  for (int j=0;j<3;j++){
    int o = ob+j;
    float acc = 0.f;
    for (int i=0;i<48;i++) acc += sh_s[nl][i]*sw[i*48+o];
    float a = Sacc[(size_t)n*48+o]*inv + acc*I48;
    a_s[(size_t)n*48+o] = a;
    atomicAdd(&csum[o], a);
    atomicAdd(&csq[o], a*a);
  }
  __syncthreads();
  if (t<96) bnpart[(size_t)blockIdx.x*96 + t] = (t<48) ? csum[t] : csq[t-48];
}

// ---------------- BN finalize: 1 block, 768 thr, 4 loads in flight ----------------
__global__ void k_bnfin2(const float* __restrict__ bnpart,
                         const float* __restrict__ g, const float* __restrict__ b,
                         float* __restrict__ kscale, float* __restrict__ kbias,
                         int nblk, int N){
  __shared__ float red[8][96];
  __shared__ float tot[96];
  int t = threadIdx.x;           // 768 threads
  int gg = t/96, o = t - gg*96;
  float a0=0.f,a1=0.f,a2=0.f,a3=0.f;
  int bk = gg;
  for (; bk+24 < nblk; bk += 32){
    a0 += bnpart[(size_t)bk*96 + o];
    a1 += bnpart[(size_t)(bk+8)*96 + o];
    a2 += bnpart[(size_t)(bk+16)*96 + o];
    a3 += bnpart[(size_t)(bk+24)*96 + o];
  }
  for (; bk < nblk; bk += 8) a0 += bnpart[(size_t)bk*96 + o];
  red[gg][o] = (a0+a1)+(a2+a3);
  __syncthreads();
  if (t<96){
    float s2 = 0.f;
    #pragma unroll
    for (int k=0;k<8;k++) s2 += red[k][t];
    tot[t] = s2;
  }
  __syncthreads();
  if (t<48){
    float mu  = tot[t]/(float)N;
    float var = tot[48+t]/(float)N - mu*mu;
    float r = rsqrtf(var + 1e-5f);
    float sc = g[t]*r;
    kscale[t] = sc;
    kbias[t]  = b[t] - mu*sc;
  }
}

// s += a_s*scale + bias ; also zero Sacc for next layer
__global__ void k_supd(float* __restrict__ s, float* __restrict__ Sacc,
                       const float* __restrict__ a_s,
                       const float* __restrict__ kscale, const float* __restrict__ kbias,
                       int total){
  int idx = blockIdx.x*blockDim.x+threadIdx.x;
  if (idx < total){
    int o = idx % 48;
    s[idx] += a_s[idx]*kscale[o] + kbias[o];
    Sacc[idx] = 0.f;
  }
}

// ---------------- output ----------------
__global__ void k_out(const float* __restrict__ s, const float* __restrict__ ows,
                      float* __restrict__ out){
  __shared__ float sh_s[48];
  int n = blockIdx.x, t = threadIdx.x;
  if (t<48) sh_s[t] = s[(size_t)n*48+t];
  __syncthreads();
  float acc = 0.f;
  for (int i=0;i<48;i++) acc += sh_s[i]*ows[i*256+t];
  out[(size_t)n*259 + 3 + t] = acc*I48;
  if (t<3) out[(size_t)n*259 + t] = 0.f;
}

extern "C" void kernel_launch(void* const* d_in, const int* in_sizes, int n_in,
                              void* d_out, int out_size, void* d_ws, size_t ws_size,
                              hipStream_t stream){
  const float* protein_coords   = (const float*)d_in[0];
  const float* protein_features = (const float*)d_in[1];
  const float* ligand_coords    = (const float*)d_in[2];
  const float* ligand_features  = (const float*)d_in[3];
  const float* t_in    = (const float*)d_in[4];
  const float* te_w1   = (const float*)d_in[5];
  const float* te_b1   = (const float*)d_in[6];
  const float* te_w2   = (const float*)d_in[7];
  const float* te_b2   = (const float*)d_in[8];
  const float* te_ln_g = (const float*)d_in[9];
  const float* te_ln_b = (const float*)d_in[10];
  const float* pe_w1   = (const float*)d_in[11];
  const float* pe_b1   = (const float*)d_in[12];
  const float* pe_ln_g = (const float*)d_in[13];
  const float* pe_ln_b = (const float*)d_in[14];
  const float* pe_w2   = (const float*)d_in[15];
  const float* pe_b2   = (const float*)d_in[16];
  const float* le_w1   = (const float*)d_in[17];
  const float* le_b1   = (const float*)d_in[18];
  const float* le_ln_g = (const float*)d_in[19];
  const float* le_ln_b = (const float*)d_in[20];
  const float* le_w2   = (const float*)d_in[21];
  const float* le_b2   = (const float*)d_in[22];
  const float* sp_w    = (const float*)d_in[23];
  const float* sp_b    = (const float*)d_in[24];
  const float* emb_w   = (const float*)d_in[25];
  const float* ee_w1   = (const float*)d_in[26];
  const float* ee_b1   = (const float*)d_in[27];
  const float* ee_w2   = (const float*)d_in[28];
  const float* ee_b2   = (const float*)d_in[29];
  const float* conv_w1 = (const float*)d_in[30];
  const float* conv_b1 = (const float*)d_in[31];
  const float* conv_w2 = (const float*)d_in[32];
  const float* conv_b2 = (const float*)d_in[33];
  const float* conv_w3 = (const float*)d_in[34];
  const float* conv_b3 = (const float*)d_in[35];
  const float* bn_gs   = (const float*)d_in[36];
  const float* bn_bs   = (const float*)d_in[37];
  const float* si_ws   = (const float*)d_in[40];
  const float* out_ws  = (const float*)d_in[43];
  const int* edge_src  = (const int*)d_in[45];
  const int* edge_dst  = (const int*)d_in[46];

  int Np = in_sizes[0]/6;
  int Nl = in_sizes[2]/3;
  int E  = in_sizes[45];
  int N  = Nl+Np;
  int L  = in_sizes[36]/48;

  float* W = (float*)d_ws;
  size_t off = 0;
  auto alloc = [&](size_t n)->float*{ float* p = W+off; off += (n+63)&~(size_t)63; return p; };
  float* temb  = alloc(64);
  float* sbuf  = alloc((size_t)N*48);
  float* ef    = alloc((size_t)E*32);
  float* degf  = alloc(N);
  float* Sacc  = alloc((size_t)N*48);
  float* a_s   = alloc((size_t)N*48);
  float* bnpart= alloc((size_t)(N/16)*96);
  float* kscale= alloc(64);
  float* kbias = alloc(64);
  _Float16* m2h = (_Float16*)alloc((size_t)L*E*128/2 + 64);
  _Float16* wbh = (_Float16*)alloc((size_t)L*NKB*1536/2 + 64);
  _Float16* w1p = (_Float16*)alloc((size_t)L*4096/2 + 64);
  _Float16* w2p = (_Float16*)alloc((size_t)L*16384/2 + 64);

  hipMemsetAsync(degf, 0, (size_t)N*sizeof(float), stream);
  hipMemsetAsync(Sacc, 0, (size_t)N*48*sizeof(float), stream);
  k_packB2<<<2048,256,0,stream>>>(conv_w3, conv_b3, wbh, L);
  k_packMLP<<<480,256,0,stream>>>(conv_w1, conv_w2, w1p, w2p, L);
  k_temb<<<1,128,0,stream>>>(t_in, te_w1, te_b1, te_w2, te_b2, te_ln_g, te_ln_b, temb);
  k_encs0<<<Np,128,0,stream>>>(protein_features, 96, pe_w1, pe_b1, pe_ln_g, pe_ln_b,
                               pe_w2, pe_b2, sp_w, sp_b, emb_w, sbuf, Nl);
  k_encs0<<<Nl,128,0,stream>>>(ligand_features, 52, le_w1, le_b1, le_ln_g, le_ln_b,
                               le_w2, le_b2, sp_w, sp_b, emb_w, sbuf, 0);
  k_edge<<<(E+1)/2,64,0,stream>>>(ligand_coords, protein_coords, edge_src, edge_dst, temb,
                                  ee_w1, ee_b1, ee_w2, ee_b2, ef, degf, E, Nl);
  dim3 mlpg(E/64, L);
  k_mlp2<<<mlpg,256,0,stream>>>(ef, w1p, conv_b1, w2p, conv_b2, m2h, E);

  dim3 mgrid(E/128, KSPL);
  for (int l=0;l<L;l++){
    k_msg5<<<mgrid,256,0,stream>>>(m2h + (size_t)l*E*128, sbuf, wbh + (size_t)l*NKB*1536,
                                   edge_src, edge_dst, Sacc, Nl);
    k_node<<<N/16,256,0,stream>>>(Sacc, degf, sbuf, si_ws + (size_t)l*2304, a_s, bnpart, N);
    k_bnfin2<<<1,768,0,stream>>>(bnpart, bn_gs + l*48, bn_bs + l*48, kscale, kbias, N/16, N);
    k_supd<<<((size_t)N*48+255)/256,256,0,stream>>>(sbuf, Sacc, a_s, kscale, kbias, N*48);
  }
  k_out<<<Nl,256,0,stream>>>(sbuf, out_ws, (float*)d_out);
}

// Round 8
// 471.103 us; speedup vs baseline: 1.5795x; 1.0242x over previous
//
#include <hip/hip_runtime.h>
#include <hip/hip_bf16.h>
#include <math.h>

#define I48 0.14433756729740643f  // 1/sqrt(48)
#define NKB 194                   // 6144 W rows + 64 bias rows, /32
#define KCH 4                     // kblks per LDS chunk (12 KiB fp16)
#define KSPL 6                    // K-split across blockIdx.y (boundaries 32-aligned)

typedef __attribute__((ext_vector_type(8))) _Float16 half8;
typedef __attribute__((ext_vector_type(4))) float f32x4;

__device__ __forceinline__ float silu_f(float x){ return x / (1.f + __expf(-x)); }

// ---------------- time embedding (1 block, 128 thr) ----------------
__global__ void k_temb(const float* __restrict__ t_in,
                       const float* __restrict__ w1, const float* __restrict__ b1,
                       const float* __restrict__ w2, const float* __restrict__ b2,
                       const float* __restrict__ g,  const float* __restrict__ b,
                       float* __restrict__ temb){
  __shared__ float emb[64], h1[128], red[128];
  __shared__ float s_mu, s_rs;
  int t = threadIdx.x;
  float tv = t_in[0];
  if (t < 64){
    int i = t & 31;
    float fr = __expf((float)i * (-9.210340371976184f/31.f));
    float a = tv * fr;
    emb[t] = (t < 32) ? sinf(a) : cosf(a);
  }
  __syncthreads();
  {
    float z = b1[t];
    for (int i=0;i<64;i++) z += emb[i]*w1[i*128+t];
    h1[t] = silu_f(z);
  }
  __syncthreads();
  float tp = 0.f;
  if (t < 64){
    tp = b2[t];
    for (int j=0;j<128;j++) tp += h1[j]*w2[j*64+t];
  }
  red[t] = (t<64)? tp : 0.f;
  __syncthreads();
  for (int st=64;st;st>>=1){ if(t<st) red[t]+=red[t+st]; __syncthreads(); }
  if (t==0) s_mu = red[0]/64.f;
  __syncthreads();
  float d = tp - s_mu;
  red[t] = (t<64)? d*d : 0.f;
  __syncthreads();
  for (int st=64;st;st>>=1){ if(t<st) red[t]+=red[t+st]; __syncthreads(); }
  if (t==0) s_rs = rsqrtf(red[0]/64.f + 1e-5f);
  __syncthreads();
  if (t<64) temb[t] = g[t]*(d*s_rs) + b[t];
}

// ------- node encoder fused with s0: x -> LN128 -> silu -> 48 -> sp_w -> emb_w*I48 -------
__global__ void k_encs0(const float* __restrict__ x, int in_dim,
                        const float* __restrict__ w1, const float* __restrict__ b1,
                        const float* __restrict__ g,  const float* __restrict__ bb,
                        const float* __restrict__ w2, const float* __restrict__ b2,
                        const float* __restrict__ spw, const float* __restrict__ spb,
                        const float* __restrict__ embw,
                        float* __restrict__ s, int row_off){
  __shared__ float sx[96], sh[128], red[128], vout[48], c48[48];
  __shared__ float s_mu, s_rs;
  int row = blockIdx.x, t = threadIdx.x;
  for (int i=t;i<in_dim;i+=128) sx[i] = x[(size_t)row*in_dim+i];
  __syncthreads();
  float z = b1[t];
  for (int i=0;i<in_dim;i++) z += sx[i]*w1[i*128+t];
  red[t]=z; __syncthreads();
  for (int st=64;st;st>>=1){ if(t<st) red[t]+=red[t+st]; __syncthreads(); }
  if(!t) s_mu = red[0]/128.f;
  __syncthreads();
  float d = z - s_mu;
  red[t]=d*d; __syncthreads();
  for (int st=64;st;st>>=1){ if(t<st) red[t]+=red[t+st]; __syncthreads(); }
  if(!t) s_rs = rsqrtf(red[0]/128.f+1e-5f);
  __syncthreads();
  float h = g[t]*(d*s_rs)+bb[t];
  sh[t] = silu_f(h);
  __syncthreads();
  if (t<48){
    float o = b2[t];
    for (int j=0;j<128;j++) o += sh[j]*w2[j*48+t];
    vout[t] = o;
  }
  __syncthreads();
  if (t<48){
    float c = spb[t];
    for (int i=0;i<48;i++) c += vout[i]*spw[i*48+t];
    c48[t] = c;
  }
  __syncthreads();
  if (t<48){
    float v = 0.f;
    for (int i=0;i<48;i++) v += c48[i]*embw[i*48+t];
    s[(size_t)(row_off+row)*48+t] = v*I48;
  }
}

// ---------------- per-edge: dist -> ef(32); also degree atomics ----------------
__global__ void k_edge(const float* __restrict__ lc, const float* __restrict__ pc,
                       const int* __restrict__ src, const int* __restrict__ dst,
                       const float* __restrict__ temb,
                       const float* __restrict__ w1, const float* __restrict__ b1,
                       const float* __restrict__ w2, const float* __restrict__ b2,
                       float* __restrict__ ef, float* __restrict__ degf,
                       int E, int Nl){
  __shared__ float sh_h[2][32];
  int t = threadIdx.x, sub = t>>5, j = t&31;
  int e = blockIdx.x*2 + sub;
  if (e < E){
    int s_ = src[e], d_ = dst[e];
    float vx = lc[(size_t)s_*3+0]-pc[(size_t)d_*6+0];
    float vy = lc[(size_t)s_*3+1]-pc[(size_t)d_*6+1];
    float vz = lc[(size_t)s_*3+2]-pc[(size_t)d_*6+2];
    float dist = sqrtf(vx*vx+vy*vy+vz*vz+1e-12f);
    float h = b1[j] + dist*w1[j];
    for (int a=0;a<64;a++) h += temb[a]*w1[(a+1)*32+j];
    sh_h[sub][j] = silu_f(h);
  }
  __syncthreads();
  if (e < E){
    float o = b2[j];
    for (int a=0;a<32;a++) o += sh_h[sub][a]*w2[a*32+j];
    ef[(size_t)e*32+j] = o;
    if (j==0) atomicAdd(&degf[Nl + dst[e]], 1.f);
  }
}

// ---------------- pack conv MLP weights into MFMA B-fragment order, fp16 ----------------
__global__ void k_packMLP(const float* __restrict__ w1, const float* __restrict__ w2,
                          _Float16* __restrict__ w1p, _Float16* __restrict__ w2p, int L){
  int tot1 = L*8*512;
  int tot2 = L*32*512;
  int total = tot1 + tot2;
  for (int idx = blockIdx.x*blockDim.x+threadIdx.x; idx < total; idx += gridDim.x*blockDim.x){
    if (idx < tot1){
      int j = idx & 7, lane = (idx>>3)&63, rest = idx>>9;
      int nt = rest & 7, l = rest >> 3;
      int k = (lane>>4)*8 + j, o = nt*16 + (lane&15);
      w1p[idx] = (_Float16)w1[((size_t)l*32 + k)*128 + o];
    } else {
      int i2 = idx - tot1;
      int j = i2 & 7, lane = (i2>>3)&63, rest = i2>>9;
      int nt = rest & 7, kb = (rest>>3)&3, l = rest >> 5;
      int k = kb*32 + (lane>>4)*8 + j, o = nt*16 + (lane&15);
      w2p[i2] = (_Float16)w2[((size_t)l*128 + k)*128 + o];
    }
  }
}

// ---------------- edge MLP via MFMA: 64 edges x 1 layer per block ----------------
__global__ __launch_bounds__(256) void k_mlp2(
    const float* __restrict__ ef,
    const _Float16* __restrict__ w1p, const float* __restrict__ b1a,
    const _Float16* __restrict__ w2p, const float* __restrict__ b2a,
    _Float16* __restrict__ m2h, int E){
  __shared__ __align__(16) _Float16 sef[64][40];
  __shared__ __align__(16) _Float16 shh[64][136];
  __shared__ float sb1[128], sb2[128];
  const int t = threadIdx.x, lane = t & 63, w = t >> 6;
  const int e0 = blockIdx.x * 64;
  const int l  = blockIdx.y;
  const _Float16* w1l = w1p + (size_t)l*4096;
  const _Float16* w2l = w2p + (size_t)l*16384;
  if (t < 128) sb1[t] = b1a[l*128 + t];
  else         sb2[t-128] = b2a[l*128 + (t-128)];
  {
    int row = t >> 2, g = t & 3;
    const float* p = ef + ((size_t)(e0+row))*32 + g*8;
    float4 p0 = *(const float4*)p, p1 = *(const float4*)(p+4);
    half8 hv;
    hv[0]=(_Float16)p0.x; hv[1]=(_Float16)p0.y; hv[2]=(_Float16)p0.z; hv[3]=(_Float16)p0.w;
    hv[4]=(_Float16)p1.x; hv[5]=(_Float16)p1.y; hv[6]=(_Float16)p1.z; hv[7]=(_Float16)p1.w;
    *(half8*)&sef[row][g*8] = hv;
  }
  __syncthreads();
  const int m = lane & 15, quad = lane >> 4;
  const int r = w*16 + m;
  half8 a1 = *(const half8*)&sef[r][quad*8];
  f32x4 acc1[8];
  #pragma unroll
  for (int nt=0; nt<8; nt++){
    half8 b = *(const half8*)(w1l + (nt*64 + lane)*8);
    f32x4 z = {0.f,0.f,0.f,0.f};
    acc1[nt] = __builtin_amdgcn_mfma_f32_16x16x32_f16(a1, b, z, 0,0,0);
  }
  #pragma unroll
  for (int nt=0; nt<8; nt++){
    float bv = sb1[nt*16 + m];
    #pragma unroll
    for (int rr=0; rr<4; rr++)
      shh[w*16 + quad*4 + rr][nt*16 + m] = (_Float16)silu_f(acc1[nt][rr] + bv);
  }
  __syncthreads();
  f32x4 acc2[8];
  #pragma unroll
  for (int nt=0;nt<8;nt++) acc2[nt] = (f32x4){0.f,0.f,0.f,0.f};
  #pragma unroll
  for (int kb=0; kb<4; kb++){
    half8 a2 = *(const half8*)&shh[r][kb*32 + quad*8];
    #pragma unroll
    for (int nt=0; nt<8; nt++){
      half8 b = *(const half8*)(w2l + ((size_t)(kb*8+nt)*64 + lane)*8);
      acc2[nt] = __builtin_amdgcn_mfma_f32_16x16x32_f16(a2, b, acc2[nt], 0,0,0);
    }
  }
  __syncthreads();
  #pragma unroll
  for (int nt=0; nt<8; nt++){
    float bv = sb2[nt*16 + m];
    #pragma unroll
    for (int rr=0; rr<4; rr++)
      shh[w*16 + quad*4 + rr][nt*16 + m] = (_Float16)silu_f(acc2[nt][rr] + bv);
  }
  __syncthreads();
  for (int q = t; q < 64*16; q += 256){
    int row = q >> 4, c = q & 15;
    half8 hv = *(const half8*)&shh[row][c*8];
    *(half8*)(m2h + ((size_t)l*E + e0 + row)*128 + c*8) = hv;
  }
}

// ---------------- pack W (+bias rows): READ-coalesced, scattered 2B writes ----------------
__global__ void k_packB2(const float* __restrict__ w3, const float* __restrict__ b3,
                         _Float16* __restrict__ wbh, int L){
  int tot1 = L*128*2304;
  int tot2 = L*64*48;
  int total = tot1 + tot2;
  for (int idx = blockIdx.x*blockDim.x+threadIdx.x; idx < total; idx += gridDim.x*blockDim.x){
    if (idx < tot1){
      int r = idx % 2304; int q = idx / 2304;
      int kk = q & 127;   int l = q >> 7;
      float v = w3[(size_t)(l*128+kk)*11520 + r];
      int i = r / 48, o = r - i*48;
      int kp = i*128 + kk;
      int kblk = kp >> 5, p = kp & 31;
      int lane = ((p>>3)<<4) + (o & 15);
      int j = p & 7;
      int nt = o >> 4;
      wbh[((((size_t)l*NKB + kblk)*3 + nt)*64 + lane)*8 + j] = (_Float16)v;
    } else {
      int i2 = idx - tot1;
      int o = i2 % 48; int q = i2 / 48;
      int ii = q & 63; int l = q >> 6;
      float v = (ii < 48) ? b3[(size_t)l*11520 + ii*48 + o] : 0.f;
      int kp = 6144 + ii;
      int kblk = kp >> 5, p = kp & 31;
      int lane = ((p>>3)<<4) + (o & 15);
      int j = p & 7;
      int nt = o >> 4;
      wbh[((((size_t)l*NKB + kblk)*3 + nt)*64 + lane)*8 + j] = (_Float16)v;
    }
  }
}

// ---------------- hot kernel v5: A-side m2 in registers; LDS only for B ----------------
__global__ __launch_bounds__(256) void k_msg5(
    const _Float16* __restrict__ m2h, const float* __restrict__ s,
    const _Float16* __restrict__ wbh,
    const int* __restrict__ src, const int* __restrict__ dst,
    float* __restrict__ Sacc, int Nl){
  __shared__ __align__(16) _Float16 sB[2][KCH*1536];   // 2 x 12 KiB
  __shared__ __align__(16) _Float16 sseq[128][72];     // 18.4 KiB (se, zero-padded)
  __shared__ int sdst[128];
  const int t = threadIdx.x, lane = t & 63, w = t >> 6;
  const int e0 = blockIdx.x * 128;
  const int by = blockIdx.y;
  const int kb0 = by*32;
  const int kb1 = (by==KSPL-1) ? NKB : kb0+32;

  for (int q = t; q < 128*9; q += 256){
    int e = q/9, g = q - e*9;
    half8 hv = {};
    if (g < 6){
      const float* sp = s + (size_t)src[e0+e]*48 + g*8;
      float4 p0 = *(const float4*)sp, p1 = *(const float4*)(sp+4);
      hv[0]=(_Float16)p0.x; hv[1]=(_Float16)p0.y; hv[2]=(_Float16)p0.z; hv[3]=(_Float16)p0.w;
      hv[4]=(_Float16)p1.x; hv[5]=(_Float16)p1.y; hv[6]=(_Float16)p1.z; hv[7]=(_Float16)p1.w;
    }
    *(half8*)&sseq[e][g*8] = hv;
  }
  if (t < 128) sdst[t] = dst[e0+t];

  const int m = lane & 15, quad = lane >> 4;
  const int r0 = w*32 + m, r1 = r0 + 16;

  half8 f0[4], f1[4];
  {
    const _Float16* base0 = m2h + (size_t)(e0+r0)*128 + quad*8;
    const _Float16* base1 = m2h + (size_t)(e0+r1)*128 + quad*8;
    #pragma unroll
    for (int sub=0; sub<4; sub++){
      f0[sub] = *(const half8*)(base0 + sub*32);
      f1[sub] = *(const half8*)(base1 + sub*32);
    }
  }

  auto stage = [&](int c){
    int kbase = kb0 + c*KCH;
    int nk = kb1 - kbase; if (nk > KCH) nk = KCH;
    int bytes = nk*3072;
    const char* g = (const char*)wbh + (size_t)kbase*3072;
    char* lb = (char*)sB[c&1];
    for (int off = w*1024; off < bytes; off += 4096){
      __builtin_amdgcn_global_load_lds(
        (const __attribute__((address_space(1))) void*)(g + off + (size_t)lane*16),
        (__attribute__((address_space(3))) void*)(lb + off), 16, 0, 0);
    }
  };
  stage(0);

  f32x4 acc00={0.f,0.f,0.f,0.f}, acc01={0.f,0.f,0.f,0.f}, acc02={0.f,0.f,0.f,0.f};
  f32x4 acc10={0.f,0.f,0.f,0.f}, acc11={0.f,0.f,0.f,0.f}, acc12={0.f,0.f,0.f,0.f};

  const int nch = (kb1-kb0+KCH-1)/KCH;
  for (int c = 0; c < nch; c++){
    __syncthreads();
    if (c+1 < nch) stage(c+1);
    int kbase = kb0 + c*KCH;
    int kbn = kb1 - kbase; if (kbn > KCH) kbn = KCH;
    const _Float16* bb = sB[c&1];
    if (kbn == KCH && kbase < 192){
      int i = kbase >> 2;
      _Float16 sv0 = sseq[r0][i], sv1 = sseq[r1][i];
      half8 s0v = {sv0,sv0,sv0,sv0,sv0,sv0,sv0,sv0};
      half8 s1v = {sv1,sv1,sv1,sv1,sv1,sv1,sv1,sv1};
      #pragma unroll
      for (int kk = 0; kk < KCH; kk++){
        half8 a0 = f0[kk] * s0v;
        half8 a1 = f1[kk] * s1v;
        const _Float16* bk = bb + kk*1536 + lane*8;
        half8 b0 = *(const half8*)(bk);
        half8 b1 = *(const half8*)(bk + 512);
        half8 b2 = *(const half8*)(bk + 1024);
        acc00 = __builtin_amdgcn_mfma_f32_16x16x32_f16(a0, b0, acc00, 0, 0, 0);
        acc01 = __builtin_amdgcn_mfma_f32_16x16x32_f16(a0, b1, acc01, 0, 0, 0);
        acc02 = __builtin_amdgcn_mfma_f32_16x16x32_f16(a0, b2, acc02, 0, 0, 0);
        acc10 = __builtin_amdgcn_mfma_f32_16x16x32_f16(a1, b0, acc10, 0, 0, 0);
        acc11 = __builtin_amdgcn_mfma_f32_16x16x32_f16(a1, b1, acc11, 0, 0, 0);
        acc12 = __builtin_amdgcn_mfma_f32_16x16x32_f16(a1, b2, acc12, 0, 0, 0);
      }
    } else {
      for (int kk = 0; kk < kbn; kk++){
        int kblk = kbase + kk;
        int ib = ((kblk-192) << 5) + quad*8;
        half8 a0 = *(const half8*)&sseq[r0][ib];
        half8 a1 = *(const half8*)&sseq[r1][ib];
        const _Float16* bk = bb + kk*1536 + lane*8;
        half8 b0 = *(const half8*)(bk);
        half8 b1 = *(const half8*)(bk + 512);
        half8 b2 = *(const half8*)(bk + 1024);
        acc00 = __builtin_amdgcn_mfma_f32_16x16x32_f16(a0, b0, acc00, 0, 0, 0);
        acc01 = __builtin_amdgcn_mfma_f32_16x16x32_f16(a0, b1, acc01, 0, 0, 0);
        acc02 = __builtin_amdgcn_mfma_f32_16x16x32_f16(a0, b2, acc02, 0, 0, 0);
        acc10 = __builtin_amdgcn_mfma_f32_16x16x32_f16(a1, b0, acc10, 0, 0, 0);
        acc11 = __builtin_amdgcn_mfma_f32_16x16x32_f16(a1, b1, acc11, 0, 0, 0);
        acc12 = __builtin_amdgcn_mfma_f32_16x16x32_f16(a1, b2, acc12, 0, 0, 0);
      }
    }
  }
  #pragma unroll
  for (int r = 0; r < 4; r++){
    int el0 = w*32 + quad*4 + r;
    int el1 = el0 + 16;
    float* p0 = Sacc + (size_t)(Nl + sdst[el0])*48 + m;
    float* p1 = Sacc + (size_t)(Nl + sdst[el1])*48 + m;
    atomicAdd(p0 +  0, acc00[r]*I48);
    atomicAdd(p0 + 16, acc01[r]*I48);
    atomicAdd(p0 + 32, acc02[r]*I48);
    atomicAdd(p1 +  0, acc10[r]*I48);
    atomicAdd(p1 + 16, acc11[r]*I48);
    atomicAdd(p1 + 32, acc12[r]*I48);
  }
}

// ------- node update: a_s = Sacc/deg + s@si_ws*I48 ; BN sums via global atomics -------
__global__ __launch_bounds__(256) void k_node2(const float* __restrict__ Sacc,
                       const float* __restrict__ degf,
                       const float* __restrict__ s, const float* __restrict__ siw,
                       float* __restrict__ a_s, float* __restrict__ bnl, int N){
  __shared__ float sh_s[16][48];
  __shared__ float sw[2304];
  __shared__ float csum[48], csq[48];
  int t = threadIdx.x;
  int n0 = blockIdx.x*16;
  for (int q=t;q<2304;q+=256) sw[q] = siw[q];
  for (int q=t;q<768;q+=256){
    int nl=q/48, i=q-nl*48;
    sh_s[nl][i] = s[(size_t)(n0+nl)*48+i];
  }
  if (t<48){ csum[t]=0.f; csq[t]=0.f; }
  __syncthreads();
  int nl = t>>4;
  int ob = (t&15)*3;
  int n = n0+nl;
  float dg = degf[n]; if (dg < 1.f) dg = 1.f;
  float inv = 1.f/dg;
  #pragma unroll
  for (int j=0;j<3;j++){
    int o = ob+j;
    float acc = 0.f;
    for (int i=0;i<48;i++) acc += sh_s[nl][i]*sw[i*48+o];
    float a = Sacc[(size_t)n*48+o]*inv + acc*I48;
    a_s[(size_t)n*48+o] = a;
    atomicAdd(&csum[o], a);
    atomicAdd(&csq[o], a*a);
  }
  __syncthreads();
  if (t<96) atomicAdd(&bnl[t], (t<48) ? csum[t] : csq[t-48]);
}

// ------- fused BN finalize (from finished global sums) + s update + Sacc zero -------
__global__ __launch_bounds__(256) void k_supd3(
    float* __restrict__ s, float* __restrict__ Sacc,
    const float* __restrict__ a_s, const float* __restrict__ bnl,
    const float* __restrict__ g, const float* __restrict__ b, int N){
  __shared__ float ksc[48], kbs[48];
  int t = threadIdx.x;
  if (t < 48){
    float su = bnl[t], sq = bnl[48+t];
    float mu  = su/(float)N;
    float var = sq/(float)N - mu*mu;
    float r = rsqrtf(var + 1e-5f);
    float sc = g[t]*r;
    ksc[t] = sc;
    kbs[t] = b[t] - mu*sc;
  }
  __syncthreads();
  size_t base = (size_t)blockIdx.x*768;
  for (int q=t; q<768; q+=256){
    int o = q % 48;
    size_t idx = base + q;
    s[idx] += a_s[idx]*ksc[o] + kbs[o];
    Sacc[idx] = 0.f;
  }
}

// ---------------- output ----------------
__global__ void k_out(const float* __restrict__ s, const float* __restrict__ ows,
                      float* __restrict__ out){
  __shared__ float sh_s[48];
  int n = blockIdx.x, t = threadIdx.x;
  if (t<48) sh_s[t] = s[(size_t)n*48+t];
  __syncthreads();
  float acc = 0.f;
  for (int i=0;i<48;i++) acc += sh_s[i]*ows[i*256+t];
  out[(size_t)n*259 + 3 + t] = acc*I48;
  if (t<3) out[(size_t)n*259 + t] = 0.f;
}

extern "C" void kernel_launch(void* const* d_in, const int* in_sizes, int n_in,
                              void* d_out, int out_size, void* d_ws, size_t ws_size,
                              hipStream_t stream){
  const float* protein_coords   = (const float*)d_in[0];
  const float* protein_features = (const float*)d_in[1];
  const float* ligand_coords    = (const float*)d_in[2];
  const float* ligand_features  = (const float*)d_in[3];
  const float* t_in    = (const float*)d_in[4];
  const float* te_w1   = (const float*)d_in[5];
  const float* te_b1   = (const float*)d_in[6];
  const float* te_w2   = (const float*)d_in[7];
  const float* te_b2   = (const float*)d_in[8];
  const float* te_ln_g = (const float*)d_in[9];
  const float* te_ln_b = (const float*)d_in[10];
  const float* pe_w1   = (const float*)d_in[11];
  const float* pe_b1   = (const float*)d_in[12];
  const float* pe_ln_g = (const float*)d_in[13];
  const float* pe_ln_b = (const float*)d_in[14];
  const float* pe_w2   = (const float*)d_in[15];
  const float* pe_b2   = (const float*)d_in[16];
  const float* le_w1   = (const float*)d_in[17];
  const float* le_b1   = (const float*)d_in[18];
  const float* le_ln_g = (const float*)d_in[19];
  const float* le_ln_b = (const float*)d_in[20];
  const float* le_w2   = (const float*)d_in[21];
  const float* le_b2   = (const float*)d_in[22];
  const float* sp_w    = (const float*)d_in[23];
  const float* sp_b    = (const float*)d_in[24];
  const float* emb_w   = (const float*)d_in[25];
  const float* ee_w1   = (const float*)d_in[26];
  const float* ee_b1   = (const float*)d_in[27];
  const float* ee_w2   = (const float*)d_in[28];
  const float* ee_b2   = (const float*)d_in[29];
  const float* conv_w1 = (const float*)d_in[30];
  const float* conv_b1 = (const float*)d_in[31];
  const float* conv_w2 = (const float*)d_in[32];
  const float* conv_b2 = (const float*)d_in[33];
  const float* conv_w3 = (const float*)d_in[34];
  const float* conv_b3 = (const float*)d_in[35];
  const float* bn_gs   = (const float*)d_in[36];
  const float* bn_bs   = (const float*)d_in[37];
  const float* si_ws   = (const float*)d_in[40];
  const float* out_ws  = (const float*)d_in[43];
  const int* edge_src  = (const int*)d_in[45];
  const int* edge_dst  = (const int*)d_in[46];

  int Np = in_sizes[0]/6;
  int Nl = in_sizes[2]/3;
  int E  = in_sizes[45];
  int N  = Nl+Np;
  int L  = in_sizes[36]/48;

  float* W = (float*)d_ws;
  size_t off = 0;
  auto alloc = [&](size_t n)->float*{ float* p = W+off; off += (n+63)&~(size_t)63; return p; };
  // degf, Sacc, bnb contiguous -> single startup memset
  float* degf  = alloc(N);
  float* Sacc  = alloc((size_t)N*48);
  float* bnb   = alloc((size_t)L*96);
  float* temb  = alloc(64);
  float* sbuf  = alloc((size_t)N*48);
  float* ef    = alloc((size_t)E*32);
  float* a_s   = alloc((size_t)N*48);
  _Float16* m2h = (_Float16*)alloc((size_t)L*E*128/2 + 64);
  _Float16* wbh = (_Float16*)alloc((size_t)L*NKB*1536/2 + 64);
  _Float16* w1p = (_Float16*)alloc((size_t)L*4096/2 + 64);
  _Float16* w2p = (_Float16*)alloc((size_t)L*16384/2 + 64);

  hipMemsetAsync(degf, 0, ((size_t)N + (size_t)N*48 + (size_t)L*96 + 192)*sizeof(float), stream);
  k_packB2<<<2048,256,0,stream>>>(conv_w3, conv_b3, wbh, L);
  k_packMLP<<<480,256,0,stream>>>(conv_w1, conv_w2, w1p, w2p, L);
  k_temb<<<1,128,0,stream>>>(t_in, te_w1, te_b1, te_w2, te_b2, te_ln_g, te_ln_b, temb);
  k_encs0<<<Np,128,0,stream>>>(protein_features, 96, pe_w1, pe_b1, pe_ln_g, pe_ln_b,
                               pe_w2, pe_b2, sp_w, sp_b, emb_w, sbuf, Nl);
  k_encs0<<<Nl,128,0,stream>>>(ligand_features, 52, le_w1, le_b1, le_ln_g, le_ln_b,
                               le_w2, le_b2, sp_w, sp_b, emb_w, sbuf, 0);
  k_edge<<<(E+1)/2,64,0,stream>>>(ligand_coords, protein_coords, edge_src, edge_dst, temb,
                                  ee_w1, ee_b1, ee_w2, ee_b2, ef, degf, E, Nl);
  dim3 mlpg(E/64, L);
  k_mlp2<<<mlpg,256,0,stream>>>(ef, w1p, conv_b1, w2p, conv_b2, m2h, E);

  dim3 mgrid(E/128, KSPL);
  for (int l=0;l<L;l++){
    k_msg5<<<mgrid,256,0,stream>>>(m2h + (size_t)l*E*128, sbuf, wbh + (size_t)l*NKB*1536,
                                   edge_src, edge_dst, Sacc, Nl);
    k_node2<<<N/16,256,0,stream>>>(Sacc, degf, sbuf, si_ws + (size_t)l*2304, a_s, bnb + l*96, N);
    k_supd3<<<N/16,256,0,stream>>>(sbuf, Sacc, a_s, bnb + l*96, bn_gs + l*48, bn_bs + l*48, N);
  }
  k_out<<<Nl,256,0,stream>>>(sbuf, out_ws, (float*)d_out);
}

// Round 9
// 463.134 us; speedup vs baseline: 1.6066x; 1.0172x over previous
//
#include <hip/hip_runtime.h>
#include <hip/hip_bf16.h>
#include <math.h>

#define I48 0.14433756729740643f  // 1/sqrt(48)
#define NKB 194                   // 6144 W rows + 64 bias rows, /32
#define KCH 4                     // kblks per LDS chunk (12 KiB fp16)
#define KSPL 6                    // K-split across blockIdx.y (boundaries 32-aligned)

typedef __attribute__((ext_vector_type(8))) _Float16 half8;
typedef __attribute__((ext_vector_type(4))) float f32x4;

__device__ __forceinline__ float silu_f(float x){ return x / (1.f + __expf(-x)); }

// ---------------- time embedding (1 block, 128 thr) ----------------
__global__ void k_temb(const float* __restrict__ t_in,
                       const float* __restrict__ w1, const float* __restrict__ b1,
                       const float* __restrict__ w2, const float* __restrict__ b2,
                       const float* __restrict__ g,  const float* __restrict__ b,
                       float* __restrict__ temb){
  __shared__ float emb[64], h1[128], red[128];
  __shared__ float s_mu, s_rs;
  int t = threadIdx.x;
  float tv = t_in[0];
  if (t < 64){
    int i = t & 31;
    float fr = __expf((float)i * (-9.210340371976184f/31.f));
    float a = tv * fr;
    emb[t] = (t < 32) ? sinf(a) : cosf(a);
  }
  __syncthreads();
  {
    float z = b1[t];
    for (int i=0;i<64;i++) z += emb[i]*w1[i*128+t];
    h1[t] = silu_f(z);
  }
  __syncthreads();
  float tp = 0.f;
  if (t < 64){
    tp = b2[t];
    for (int j=0;j<128;j++) tp += h1[j]*w2[j*64+t];
  }
  red[t] = (t<64)? tp : 0.f;
  __syncthreads();
  for (int st=64;st;st>>=1){ if(t<st) red[t]+=red[t+st]; __syncthreads(); }
  if (t==0) s_mu = red[0]/64.f;
  __syncthreads();
  float d = tp - s_mu;
  red[t] = (t<64)? d*d : 0.f;
  __syncthreads();
  for (int st=64;st;st>>=1){ if(t<st) red[t]+=red[t+st]; __syncthreads(); }
  if (t==0) s_rs = rsqrtf(red[0]/64.f + 1e-5f);
  __syncthreads();
  if (t<64) temb[t] = g[t]*(d*s_rs) + b[t];
}

// ------- node encoder fused with s0: x -> LN128 -> silu -> 48 -> sp_w -> emb_w*I48 -------
__global__ void k_encs0(const float* __restrict__ x, int in_dim,
                        const float* __restrict__ w1, const float* __restrict__ b1,
                        const float* __restrict__ g,  const float* __restrict__ bb,
                        const float* __restrict__ w2, const float* __restrict__ b2,
                        const float* __restrict__ spw, const float* __restrict__ spb,
                        const float* __restrict__ embw,
                        float* __restrict__ s, int row_off){
  __shared__ float sx[96], sh[128], red[128], vout[48], c48[48];
  __shared__ float s_mu, s_rs;
  int row = blockIdx.x, t = threadIdx.x;
  for (int i=t;i<in_dim;i+=128) sx[i] = x[(size_t)row*in_dim+i];
  __syncthreads();
  float z = b1[t];
  for (int i=0;i<in_dim;i++) z += sx[i]*w1[i*128+t];
  red[t]=z; __syncthreads();
  for (int st=64;st;st>>=1){ if(t<st) red[t]+=red[t+st]; __syncthreads(); }
  if(!t) s_mu = red[0]/128.f;
  __syncthreads();
  float d = z - s_mu;
  red[t]=d*d; __syncthreads();
  for (int st=64;st;st>>=1){ if(t<st) red[t]+=red[t+st]; __syncthreads(); }
  if(!t) s_rs = rsqrtf(red[0]/128.f+1e-5f);
  __syncthreads();
  float h = g[t]*(d*s_rs)+bb[t];
  sh[t] = silu_f(h);
  __syncthreads();
  if (t<48){
    float o = b2[t];
    for (int j=0;j<128;j++) o += sh[j]*w2[j*48+t];
    vout[t] = o;
  }
  __syncthreads();
  if (t<48){
    float c = spb[t];
    for (int i=0;i<48;i++) c += vout[i]*spw[i*48+t];
    c48[t] = c;
  }
  __syncthreads();
  if (t<48){
    float v = 0.f;
    for (int i=0;i<48;i++) v += c48[i]*embw[i*48+t];
    s[(size_t)(row_off+row)*48+t] = v*I48;
  }
}

// ---------------- per-edge: dist -> ef(32); also degree atomics ----------------
__global__ void k_edge(const float* __restrict__ lc, const float* __restrict__ pc,
                       const int* __restrict__ src, const int* __restrict__ dst,
                       const float* __restrict__ temb,
                       const float* __restrict__ w1, const float* __restrict__ b1,
                       const float* __restrict__ w2, const float* __restrict__ b2,
                       float* __restrict__ ef, float* __restrict__ degf,
                       int E, int Nl){
  __shared__ float sh_h[2][32];
  int t = threadIdx.x, sub = t>>5, j = t&31;
  int e = blockIdx.x*2 + sub;
  if (e < E){
    int s_ = src[e], d_ = dst[e];
    float vx = lc[(size_t)s_*3+0]-pc[(size_t)d_*6+0];
    float vy = lc[(size_t)s_*3+1]-pc[(size_t)d_*6+1];
    float vz = lc[(size_t)s_*3+2]-pc[(size_t)d_*6+2];
    float dist = sqrtf(vx*vx+vy*vy+vz*vz+1e-12f);
    float h = b1[j] + dist*w1[j];
    for (int a=0;a<64;a++) h += temb[a]*w1[(a+1)*32+j];
    sh_h[sub][j] = silu_f(h);
  }
  __syncthreads();
  if (e < E){
    float o = b2[j];
    for (int a=0;a<32;a++) o += sh_h[sub][a]*w2[a*32+j];
    ef[(size_t)e*32+j] = o;
    if (j==0) atomicAdd(&degf[Nl + dst[e]], 1.f);
  }
}

// ---------------- pack conv MLP weights into MFMA B-fragment order, fp16 ----------------
__global__ void k_packMLP(const float* __restrict__ w1, const float* __restrict__ w2,
                          _Float16* __restrict__ w1p, _Float16* __restrict__ w2p, int L){
  int tot1 = L*8*512;
  int tot2 = L*32*512;
  int total = tot1 + tot2;
  for (int idx = blockIdx.x*blockDim.x+threadIdx.x; idx < total; idx += gridDim.x*blockDim.x){
    if (idx < tot1){
      int j = idx & 7, lane = (idx>>3)&63, rest = idx>>9;
      int nt = rest & 7, l = rest >> 3;
      int k = (lane>>4)*8 + j, o = nt*16 + (lane&15);
      w1p[idx] = (_Float16)w1[((size_t)l*32 + k)*128 + o];
    } else {
      int i2 = idx - tot1;
      int j = i2 & 7, lane = (i2>>3)&63, rest = i2>>9;
      int nt = rest & 7, kb = (rest>>3)&3, l = rest >> 5;
      int k = kb*32 + (lane>>4)*8 + j, o = nt*16 + (lane&15);
      w2p[i2] = (_Float16)w2[((size_t)l*128 + k)*128 + o];
    }
  }
}

// ---------------- edge MLP via MFMA: 64 edges x 1 layer per block ----------------
__global__ __launch_bounds__(256) void k_mlp2(
    const float* __restrict__ ef,
    const _Float16* __restrict__ w1p, const float* __restrict__ b1a,
    const _Float16* __restrict__ w2p, const float* __restrict__ b2a,
    _Float16* __restrict__ m2h, int E){
  __shared__ __align__(16) _Float16 sef[64][40];
  __shared__ __align__(16) _Float16 shh[64][136];
  __shared__ float sb1[128], sb2[128];
  const int t = threadIdx.x, lane = t & 63, w = t >> 6;
  const int e0 = blockIdx.x * 64;
  const int l  = blockIdx.y;
  const _Float16* w1l = w1p + (size_t)l*4096;
  const _Float16* w2l = w2p + (size_t)l*16384;
  if (t < 128) sb1[t] = b1a[l*128 + t];
  else         sb2[t-128] = b2a[l*128 + (t-128)];
  {
    int row = t >> 2, g = t & 3;
    const float* p = ef + ((size_t)(e0+row))*32 + g*8;
    float4 p0 = *(const float4*)p, p1 = *(const float4*)(p+4);
    half8 hv;
    hv[0]=(_Float16)p0.x; hv[1]=(_Float16)p0.y; hv[2]=(_Float16)p0.z; hv[3]=(_Float16)p0.w;
    hv[4]=(_Float16)p1.x; hv[5]=(_Float16)p1.y; hv[6]=(_Float16)p1.z; hv[7]=(_Float16)p1.w;
    *(half8*)&sef[row][g*8] = hv;
  }
  __syncthreads();
  const int m = lane & 15, quad = lane >> 4;
  const int r = w*16 + m;
  half8 a1 = *(const half8*)&sef[r][quad*8];
  f32x4 acc1[8];
  #pragma unroll
  for (int nt=0; nt<8; nt++){
    half8 b = *(const half8*)(w1l + (nt*64 + lane)*8);
    f32x4 z = {0.f,0.f,0.f,0.f};
    acc1[nt] = __builtin_amdgcn_mfma_f32_16x16x32_f16(a1, b, z, 0,0,0);
  }
  #pragma unroll
  for (int nt=0; nt<8; nt++){
    float bv = sb1[nt*16 + m];
    #pragma unroll
    for (int rr=0; rr<4; rr++)
      shh[w*16 + quad*4 + rr][nt*16 + m] = (_Float16)silu_f(acc1[nt][rr] + bv);
  }
  __syncthreads();
  f32x4 acc2[8];
  #pragma unroll
  for (int nt=0;nt<8;nt++) acc2[nt] = (f32x4){0.f,0.f,0.f,0.f};
  #pragma unroll
  for (int kb=0; kb<4; kb++){
    half8 a2 = *(const half8*)&shh[r][kb*32 + quad*8];
    #pragma unroll
    for (int nt=0; nt<8; nt++){
      half8 b = *(const half8*)(w2l + ((size_t)(kb*8+nt)*64 + lane)*8);
      acc2[nt] = __builtin_amdgcn_mfma_f32_16x16x32_f16(a2, b, acc2[nt], 0,0,0);
    }
  }
  __syncthreads();
  #pragma unroll
  for (int nt=0; nt<8; nt++){
    float bv = sb2[nt*16 + m];
    #pragma unroll
    for (int rr=0; rr<4; rr++)
      shh[w*16 + quad*4 + rr][nt*16 + m] = (_Float16)silu_f(acc2[nt][rr] + bv);
  }
  __syncthreads();
  for (int q = t; q < 64*16; q += 256){
    int row = q >> 4, c = q & 15;
    half8 hv = *(const half8*)&shh[row][c*8];
    *(half8*)(m2h + ((size_t)l*E + e0 + row)*128 + c*8) = hv;
  }
}

// ---------------- pack W (+bias rows): READ-coalesced, scattered 2B writes ----------------
__global__ void k_packB2(const float* __restrict__ w3, const float* __restrict__ b3,
                         _Float16* __restrict__ wbh, int L){
  int tot1 = L*128*2304;
  int tot2 = L*64*48;
  int total = tot1 + tot2;
  for (int idx = blockIdx.x*blockDim.x+threadIdx.x; idx < total; idx += gridDim.x*blockDim.x){
    if (idx < tot1){
      int r = idx % 2304; int q = idx / 2304;
      int kk = q & 127;   int l = q >> 7;
      float v = w3[(size_t)(l*128+kk)*11520 + r];
      int i = r / 48, o = r - i*48;
      int kp = i*128 + kk;
      int kblk = kp >> 5, p = kp & 31;
      int lane = ((p>>3)<<4) + (o & 15);
      int j = p & 7;
      int nt = o >> 4;
      wbh[((((size_t)l*NKB + kblk)*3 + nt)*64 + lane)*8 + j] = (_Float16)v;
    } else {
      int i2 = idx - tot1;
      int o = i2 % 48; int q = i2 / 48;
      int ii = q & 63; int l = q >> 6;
      float v = (ii < 48) ? b3[(size_t)l*11520 + ii*48 + o] : 0.f;
      int kp = 6144 + ii;
      int kblk = kp >> 5, p = kp & 31;
      int lane = ((p>>3)<<4) + (o & 15);
      int j = p & 7;
      int nt = o >> 4;
      wbh[((((size_t)l*NKB + kblk)*3 + nt)*64 + lane)*8 + j] = (_Float16)v;
    }
  }
}

// ---- hot kernel v6: deferred-BN se reconstruction; A-side m2 in regs; LDS only for B ----
__global__ __launch_bounds__(256) void k_msg6(
    const _Float16* __restrict__ m2h, const float* __restrict__ s,
    const float* __restrict__ a_s, const float* __restrict__ bnlp,
    const float* __restrict__ gp, const float* __restrict__ bp, int apply, int N,
    const _Float16* __restrict__ wbh,
    const int* __restrict__ src, const int* __restrict__ dst,
    float* __restrict__ Sacc, int Nl){
  __shared__ __align__(16) _Float16 sB[2][KCH*1536];   // 2 x 12 KiB
  __shared__ __align__(16) _Float16 sseq[128][72];     // 18.4 KiB (se, zero-padded)
  __shared__ int sdst[128];
  __shared__ float ksc[48], kbs[48];
  const int t = threadIdx.x, lane = t & 63, w = t >> 6;
  const int e0 = blockIdx.x * 128;
  const int by = blockIdx.y;
  const int kb0 = by*32;
  const int kb1 = (by==KSPL-1) ? NKB : kb0+32;

  if (t < 48){
    if (apply){
      float su = bnlp[t], sq = bnlp[48+t];
      float mu  = su/(float)N;
      float var = sq/(float)N - mu*mu;
      float r = rsqrtf(var + 1e-5f);
      float sc = gp[t]*r;
      ksc[t] = sc; kbs[t] = bp[t] - mu*sc;
    } else { ksc[t]=0.f; kbs[t]=0.f; }
  }
  if (t < 128) sdst[t] = dst[e0+t];
  __syncthreads();

  for (int q = t; q < 128*9; q += 256){
    int e = q/9, g = q - e*9;
    half8 hv = {};
    if (g < 6){
      size_t base = (size_t)src[e0+e]*48 + g*8;
      const float* sp = s + base;
      if (apply){
        const float* ap = a_s + base;
        #pragma unroll
        for (int j=0;j<8;j++){
          int o = g*8+j;
          hv[j] = (_Float16)(sp[j] + ap[j]*ksc[o] + kbs[o]);
        }
      } else {
        #pragma unroll
        for (int j=0;j<8;j++) hv[j] = (_Float16)sp[j];
      }
    }
    *(half8*)&sseq[e][g*8] = hv;
  }

  const int m = lane & 15, quad = lane >> 4;
  const int r0 = w*32 + m, r1 = r0 + 16;

  half8 f0[4], f1[4];
  {
    const _Float16* base0 = m2h + (size_t)(e0+r0)*128 + quad*8;
    const _Float16* base1 = m2h + (size_t)(e0+r1)*128 + quad*8;
    #pragma unroll
    for (int sub=0; sub<4; sub++){
      f0[sub] = *(const half8*)(base0 + sub*32);
      f1[sub] = *(const half8*)(base1 + sub*32);
    }
  }

  auto stage = [&](int c){
    int kbase = kb0 + c*KCH;
    int nk = kb1 - kbase; if (nk > KCH) nk = KCH;
    int bytes = nk*3072;
    const char* g = (const char*)wbh + (size_t)kbase*3072;
    char* lb = (char*)sB[c&1];
    for (int off = w*1024; off < bytes; off += 4096){
      __builtin_amdgcn_global_load_lds(
        (const __attribute__((address_space(1))) void*)(g + off + (size_t)lane*16),
        (__attribute__((address_space(3))) void*)(lb + off), 16, 0, 0);
    }
  };
  stage(0);

  f32x4 acc00={0.f,0.f,0.f,0.f}, acc01={0.f,0.f,0.f,0.f}, acc02={0.f,0.f,0.f,0.f};
  f32x4 acc10={0.f,0.f,0.f,0.f}, acc11={0.f,0.f,0.f,0.f}, acc12={0.f,0.f,0.f,0.f};

  const int nch = (kb1-kb0+KCH-1)/KCH;
  for (int c = 0; c < nch; c++){
    __syncthreads();
    if (c+1 < nch) stage(c+1);
    int kbase = kb0 + c*KCH;
    int kbn = kb1 - kbase; if (kbn > KCH) kbn = KCH;
    const _Float16* bb = sB[c&1];
    if (kbn == KCH && kbase < 192){
      int i = kbase >> 2;
      _Float16 sv0 = sseq[r0][i], sv1 = sseq[r1][i];
      half8 s0v = {sv0,sv0,sv0,sv0,sv0,sv0,sv0,sv0};
      half8 s1v = {sv1,sv1,sv1,sv1,sv1,sv1,sv1,sv1};
      #pragma unroll
      for (int kk = 0; kk < KCH; kk++){
        half8 a0 = f0[kk] * s0v;
        half8 a1 = f1[kk] * s1v;
        const _Float16* bk = bb + kk*1536 + lane*8;
        half8 b0 = *(const half8*)(bk);
        half8 b1 = *(const half8*)(bk + 512);
        half8 b2 = *(const half8*)(bk + 1024);
        acc00 = __builtin_amdgcn_mfma_f32_16x16x32_f16(a0, b0, acc00, 0, 0, 0);
        acc01 = __builtin_amdgcn_mfma_f32_16x16x32_f16(a0, b1, acc01, 0, 0, 0);
        acc02 = __builtin_amdgcn_mfma_f32_16x16x32_f16(a0, b2, acc02, 0, 0, 0);
        acc10 = __builtin_amdgcn_mfma_f32_16x16x32_f16(a1, b0, acc10, 0, 0, 0);
        acc11 = __builtin_amdgcn_mfma_f32_16x16x32_f16(a1, b1, acc11, 0, 0, 0);
        acc12 = __builtin_amdgcn_mfma_f32_16x16x32_f16(a1, b2, acc12, 0, 0, 0);
      }
    } else {
      for (int kk = 0; kk < kbn; kk++){
        int kblk = kbase + kk;
        int ib = ((kblk-192) << 5) + quad*8;
        half8 a0 = *(const half8*)&sseq[r0][ib];
        half8 a1 = *(const half8*)&sseq[r1][ib];
        const _Float16* bk = bb + kk*1536 + lane*8;
        half8 b0 = *(const half8*)(bk);
        half8 b1 = *(const half8*)(bk + 512);
        half8 b2 = *(const half8*)(bk + 1024);
        acc00 = __builtin_amdgcn_mfma_f32_16x16x32_f16(a0, b0, acc00, 0, 0, 0);
        acc01 = __builtin_amdgcn_mfma_f32_16x16x32_f16(a0, b1, acc01, 0, 0, 0);
        acc02 = __builtin_amdgcn_mfma_f32_16x16x32_f16(a0, b2, acc02, 0, 0, 0);
        acc10 = __builtin_amdgcn_mfma_f32_16x16x32_f16(a1, b0, acc10, 0, 0, 0);
        acc11 = __builtin_amdgcn_mfma_f32_16x16x32_f16(a1, b1, acc11, 0, 0, 0);
        acc12 = __builtin_amdgcn_mfma_f32_16x16x32_f16(a1, b2, acc12, 0, 0, 0);
      }
    }
  }
  #pragma unroll
  for (int r = 0; r < 4; r++){
    int el0 = w*32 + quad*4 + r;
    int el1 = el0 + 16;
    float* p0 = Sacc + (size_t)(Nl + sdst[el0])*48 + m;
    float* p1 = Sacc + (size_t)(Nl + sdst[el1])*48 + m;
    atomicAdd(p0 +  0, acc00[r]*I48);
    atomicAdd(p0 + 16, acc01[r]*I48);
    atomicAdd(p0 + 32, acc02[r]*I48);
    atomicAdd(p1 +  0, acc10[r]*I48);
    atomicAdd(p1 + 16, acc11[r]*I48);
    atomicAdd(p1 + 32, acc12[r]*I48);
  }
}

// ---- node update v3: reconstruct+persist s, self-term, a_s, BN sums, Sacc zero ----
__global__ __launch_bounds__(256) void k_node3(float* __restrict__ Sacc,
                       const float* __restrict__ degf,
                       float* __restrict__ s, const float* __restrict__ siw,
                       float* __restrict__ a_s,
                       const float* __restrict__ bnlp, const float* __restrict__ gp,
                       const float* __restrict__ bp, int apply,
                       float* __restrict__ bnl, int N){
  __shared__ float sh_s[16][48];
  __shared__ float sw[2304];
  __shared__ float csum[48], csq[48];
  __shared__ float ksc[48], kbs[48];
  int t = threadIdx.x;
  int n0 = blockIdx.x*16;
  if (t < 48){
    if (apply){
      float su = bnlp[t], sq = bnlp[48+t];
      float mu  = su/(float)N;
      float var = sq/(float)N - mu*mu;
      float r = rsqrtf(var + 1e-5f);
      float sc = gp[t]*r;
      ksc[t] = sc; kbs[t] = bp[t] - mu*sc;
    } else { ksc[t]=0.f; kbs[t]=0.f; }
    csum[t]=0.f; csq[t]=0.f;
  }
  for (int q=t;q<2304;q+=256) sw[q] = siw[q];
  __syncthreads();
  for (int q=t;q<768;q+=256){
    int nl=q/48, o=q-nl*48;
    size_t idx = (size_t)(n0+nl)*48+o;
    float v = s[idx];
    if (apply){
      v += a_s[idx]*ksc[o] + kbs[o];
      s[idx] = v;            // persist T_l
    }
    sh_s[nl][o] = v;
  }
  __syncthreads();
  int nl = t>>4;
  int ob = (t&15)*3;
  int n = n0+nl;
  float dg = degf[n]; if (dg < 1.f) dg = 1.f;
  float inv = 1.f/dg;
  #pragma unroll
  for (int j=0;j<3;j++){
    int o = ob+j;
    size_t idx = (size_t)n*48+o;
    float acc = 0.f;
    for (int i=0;i<48;i++) acc += sh_s[nl][i]*sw[i*48+o];
    float a = Sacc[idx]*inv + acc*I48;
    Sacc[idx] = 0.f;         // ready for next layer
    a_s[idx] = a;
    atomicAdd(&csum[o], a);
    atomicAdd(&csq[o], a*a);
  }
  __syncthreads();
  if (t<96) atomicAdd(&bnl[t], (t<48) ? csum[t] : csq[t-48]);
}

// ------- output with final deferred update: [0,0,0, (s_final @ out_ws)*I48] -------
__global__ void k_out2(const float* __restrict__ s, const float* __restrict__ a_s,
                       const float* __restrict__ bnlp, const float* __restrict__ gp,
                       const float* __restrict__ bp, int N,
                       const float* __restrict__ ows, float* __restrict__ out){
  __shared__ float sh_s[48];
  __shared__ float ksc[48], kbs[48];
  int n = blockIdx.x, t = threadIdx.x;
  if (t < 48){
    float su = bnlp[t], sq = bnlp[48+t];
    float mu  = su/(float)N;
    float var = sq/(float)N - mu*mu;
    float r = rsqrtf(var + 1e-5f);
    float sc = gp[t]*r;
    ksc[t] = sc; kbs[t] = bp[t] - mu*sc;
  }
  __syncthreads();
  if (t<48){
    size_t idx = (size_t)n*48+t;
    sh_s[t] = s[idx] + a_s[idx]*ksc[t] + kbs[t];
  }
  __syncthreads();
  float acc = 0.f;
  for (int i=0;i<48;i++) acc += sh_s[i]*ows[i*256+t];
  out[(size_t)n*259 + 3 + t] = acc*I48;
  if (t<3) out[(size_t)n*259 + t] = 0.f;
}

extern "C" void kernel_launch(void* const* d_in, const int* in_sizes, int n_in,
                              void* d_out, int out_size, void* d_ws, size_t ws_size,
                              hipStream_t stream){
  const float* protein_coords   = (const float*)d_in[0];
  const float* protein_features = (const float*)d_in[1];
  const float* ligand_coords    = (const float*)d_in[2];
  const float* ligand_features  = (const float*)d_in[3];
  const float* t_in    = (const float*)d_in[4];
  const float* te_w1   = (const float*)d_in[5];
  const float* te_b1   = (const float*)d_in[6];
  const float* te_w2   = (const float*)d_in[7];
  const float* te_b2   = (const float*)d_in[8];
  const float* te_ln_g = (const float*)d_in[9];
  const float* te_ln_b = (const float*)d_in[10];
  const float* pe_w1   = (const float*)d_in[11];
  const float* pe_b1   = (const float*)d_in[12];
  const float* pe_ln_g = (const float*)d_in[13];
  const float* pe_ln_b = (const float*)d_in[14];
  const float* pe_w2   = (const float*)d_in[15];
  const float* pe_b2   = (const float*)d_in[16];
  const float* le_w1   = (const float*)d_in[17];
  const float* le_b1   = (const float*)d_in[18];
  const float* le_ln_g = (const float*)d_in[19];
  const float* le_ln_b = (const float*)d_in[20];
  const float* le_w2   = (const float*)d_in[21];
  const float* le_b2   = (const float*)d_in[22];
  const float* sp_w    = (const float*)d_in[23];
  const float* sp_b    = (const float*)d_in[24];
  const float* emb_w   = (const float*)d_in[25];
  const float* ee_w1   = (const float*)d_in[26];
  const float* ee_b1   = (const float*)d_in[27];
  const float* ee_w2   = (const float*)d_in[28];
  const float* ee_b2   = (const float*)d_in[29];
  const float* conv_w1 = (const float*)d_in[30];
  const float* conv_b1 = (const float*)d_in[31];
  const float* conv_w2 = (const float*)d_in[32];
  const float* conv_b2 = (const float*)d_in[33];
  const float* conv_w3 = (const float*)d_in[34];
  const float* conv_b3 = (const float*)d_in[35];
  const float* bn_gs   = (const float*)d_in[36];
  const float* bn_bs   = (const float*)d_in[37];
  const float* si_ws   = (const float*)d_in[40];
  const float* out_ws  = (const float*)d_in[43];
  const int* edge_src  = (const int*)d_in[45];
  const int* edge_dst  = (const int*)d_in[46];

  int Np = in_sizes[0]/6;
  int Nl = in_sizes[2]/3;
  int E  = in_sizes[45];
  int N  = Nl+Np;
  int L  = in_sizes[36]/48;

  float* W = (float*)d_ws;
  size_t off = 0;
  auto alloc = [&](size_t n)->float*{ float* p = W+off; off += (n+63)&~(size_t)63; return p; };
  // degf, Sacc, bnb contiguous -> single startup memset
  float* degf  = alloc(N);
  float* Sacc  = alloc((size_t)N*48);
  float* bnb   = alloc((size_t)L*96);
  float* temb  = alloc(64);
  float* sbuf  = alloc((size_t)N*48);
  float* ef    = alloc((size_t)E*32);
  float* a_s   = alloc((size_t)N*48);
  _Float16* m2h = (_Float16*)alloc((size_t)L*E*128/2 + 64);
  _Float16* wbh = (_Float16*)alloc((size_t)L*NKB*1536/2 + 64);
  _Float16* w1p = (_Float16*)alloc((size_t)L*4096/2 + 64);
  _Float16* w2p = (_Float16*)alloc((size_t)L*16384/2 + 64);

  hipMemsetAsync(degf, 0, ((size_t)N + (size_t)N*48 + (size_t)L*96 + 192)*sizeof(float), stream);
  k_packB2<<<2048,256,0,stream>>>(conv_w3, conv_b3, wbh, L);
  k_packMLP<<<480,256,0,stream>>>(conv_w1, conv_w2, w1p, w2p, L);
  k_temb<<<1,128,0,stream>>>(t_in, te_w1, te_b1, te_w2, te_b2, te_ln_g, te_ln_b, temb);
  k_encs0<<<Np,128,0,stream>>>(protein_features, 96, pe_w1, pe_b1, pe_ln_g, pe_ln_b,
                               pe_w2, pe_b2, sp_w, sp_b, emb_w, sbuf, Nl);
  k_encs0<<<Nl,128,0,stream>>>(ligand_features, 52, le_w1, le_b1, le_ln_g, le_ln_b,
                               le_w2, le_b2, sp_w, sp_b, emb_w, sbuf, 0);
  k_edge<<<(E+1)/2,64,0,stream>>>(ligand_coords, protein_coords, edge_src, edge_dst, temb,
                                  ee_w1, ee_b1, ee_w2, ee_b2, ef, degf, E, Nl);
  dim3 mlpg(E/64, L);
  k_mlp2<<<mlpg,256,0,stream>>>(ef, w1p, conv_b1, w2p, conv_b2, m2h, E);

  dim3 mgrid(E/128, KSPL);
  for (int l=0;l<L;l++){
    const float* bnlp = (l>0) ? (bnb + (l-1)*96) : bnb;
    const float* gp   = (l>0) ? (bn_gs + (l-1)*48) : bn_gs;
    const float* bp   = (l>0) ? (bn_bs + (l-1)*48) : bn_bs;
    int apply = (l>0) ? 1 : 0;
    k_msg6<<<mgrid,256,0,stream>>>(m2h + (size_t)l*E*128, sbuf, a_s, bnlp, gp, bp, apply, N,
                                   wbh + (size_t)l*NKB*1536, edge_src, edge_dst, Sacc, Nl);
    k_node3<<<N/16,256,0,stream>>>(Sacc, degf, sbuf, si_ws + (size_t)l*2304, a_s,
                                   bnlp, gp, bp, apply, bnb + l*96, N);
  }
  k_out2<<<Nl,256,0,stream>>>(sbuf, a_s, bnb + (L-1)*96, bn_gs + (L-1)*48, bn_bs + (L-1)*48,
                              N, out_ws, (float*)d_out);
}

// Round 10
// 449.098 us; speedup vs baseline: 1.6568x; 1.0313x over previous
//
#include <hip/hip_runtime.h>
#include <hip/hip_bf16.h>
#include <math.h>

#define I48 0.14433756729740643f  // 1/sqrt(48)
#define NKB 194                   // 6144 W rows + 64 bias rows, /32
#define KCH 4                     // kblks per LDS chunk (12 KiB fp16)
#define KSPL 6                    // K-split across blockIdx.y (boundaries 32-aligned)

typedef __attribute__((ext_vector_type(8))) _Float16 half8;
typedef __attribute__((ext_vector_type(4))) float f32x4;

__device__ __forceinline__ float silu_f(float x){ return x / (1.f + __expf(-x)); }

// ---------------- time embedding (1 block, 128 thr) ----------------
__global__ void k_temb(const float* __restrict__ t_in,
                       const float* __restrict__ w1, const float* __restrict__ b1,
                       const float* __restrict__ w2, const float* __restrict__ b2,
                       const float* __restrict__ g,  const float* __restrict__ b,
                       float* __restrict__ temb){
  __shared__ float emb[64], h1[128], red[128];
  __shared__ float s_mu, s_rs;
  int t = threadIdx.x;
  float tv = t_in[0];
  if (t < 64){
    int i = t & 31;
    float fr = __expf((float)i * (-9.210340371976184f/31.f));
    float a = tv * fr;
    emb[t] = (t < 32) ? sinf(a) : cosf(a);
  }
  __syncthreads();
  {
    float z = b1[t];
    for (int i=0;i<64;i++) z += emb[i]*w1[i*128+t];
    h1[t] = silu_f(z);
  }
  __syncthreads();
  float tp = 0.f;
  if (t < 64){
    tp = b2[t];
    for (int j=0;j<128;j++) tp += h1[j]*w2[j*64+t];
  }
  red[t] = (t<64)? tp : 0.f;
  __syncthreads();
  for (int st=64;st;st>>=1){ if(t<st) red[t]+=red[t+st]; __syncthreads(); }
  if (t==0) s_mu = red[0]/64.f;
  __syncthreads();
  float d = tp - s_mu;
  red[t] = (t<64)? d*d : 0.f;
  __syncthreads();
  for (int st=64;st;st>>=1){ if(t<st) red[t]+=red[t+st]; __syncthreads(); }
  if (t==0) s_rs = rsqrtf(red[0]/64.f + 1e-5f);
  __syncthreads();
  if (t<64) temb[t] = g[t]*(d*s_rs) + b[t];
}

// ------- merged node encoder (ligand rows < Nl, protein rows >= Nl) fused with s0 -------
__global__ void k_encall(const float* __restrict__ pf, const float* __restrict__ lf, int Nl,
    const float* __restrict__ pw1, const float* __restrict__ pb1,
    const float* __restrict__ pg,  const float* __restrict__ pbb,
    const float* __restrict__ pw2, const float* __restrict__ pb2,
    const float* __restrict__ lw1, const float* __restrict__ lb1,
    const float* __restrict__ lg,  const float* __restrict__ lbb,
    const float* __restrict__ lw2, const float* __restrict__ lb2,
    const float* __restrict__ spw, const float* __restrict__ spb,
    const float* __restrict__ embw, float* __restrict__ s){
  __shared__ float sx[96], sh[128], red[128], vout[48], c48[48];
  __shared__ float s_mu, s_rs;
  int row = blockIdx.x, t = threadIdx.x;
  bool lig = row < Nl;
  int in_dim = lig ? 52 : 96;
  const float* x  = lig ? (lf + (size_t)row*52) : (pf + (size_t)(row-Nl)*96);
  const float* w1 = lig ? lw1 : pw1;
  const float* b1 = lig ? lb1 : pb1;
  const float* g  = lig ? lg  : pg;
  const float* bb = lig ? lbb : pbb;
  const float* w2 = lig ? lw2 : pw2;
  const float* b2 = lig ? lb2 : pb2;
  for (int i=t;i<in_dim;i+=128) sx[i] = x[i];
  __syncthreads();
  float z = b1[t];
  for (int i=0;i<in_dim;i++) z += sx[i]*w1[i*128+t];
  red[t]=z; __syncthreads();
  for (int st=64;st;st>>=1){ if(t<st) red[t]+=red[t+st]; __syncthreads(); }
  if(!t) s_mu = red[0]/128.f;
  __syncthreads();
  float d = z - s_mu;
  red[t]=d*d; __syncthreads();
  for (int st=64;st;st>>=1){ if(t<st) red[t]+=red[t+st]; __syncthreads(); }
  if(!t) s_rs = rsqrtf(red[0]/128.f+1e-5f);
  __syncthreads();
  float h = g[t]*(d*s_rs)+bb[t];
  sh[t] = silu_f(h);
  __syncthreads();
  if (t<48){
    float o = b2[t];
    for (int j=0;j<128;j++) o += sh[j]*w2[j*48+t];
    vout[t] = o;
  }
  __syncthreads();
  if (t<48){
    float c = spb[t];
    for (int i=0;i<48;i++) c += vout[i]*spw[i*48+t];
    c48[t] = c;
  }
  __syncthreads();
  if (t<48){
    float v = 0.f;
    for (int i=0;i<48;i++) v += c48[i]*embw[i*48+t];
    s[(size_t)row*48+t] = v*I48;
  }
}

// ---------------- per-edge: dist -> ef(32); also degree atomics ----------------
__global__ void k_edge(const float* __restrict__ lc, const float* __restrict__ pc,
                       const int* __restrict__ src, const int* __restrict__ dst,
                       const float* __restrict__ temb,
                       const float* __restrict__ w1, const float* __restrict__ b1,
                       const float* __restrict__ w2, const float* __restrict__ b2,
                       float* __restrict__ ef, float* __restrict__ degf,
                       int E, int Nl){
  __shared__ float sh_h[2][32];
  int t = threadIdx.x, sub = t>>5, j = t&31;
  int e = blockIdx.x*2 + sub;
  if (e < E){
    int s_ = src[e], d_ = dst[e];
    float vx = lc[(size_t)s_*3+0]-pc[(size_t)d_*6+0];
    float vy = lc[(size_t)s_*3+1]-pc[(size_t)d_*6+1];
    float vz = lc[(size_t)s_*3+2]-pc[(size_t)d_*6+2];
    float dist = sqrtf(vx*vx+vy*vy+vz*vz+1e-12f);
    float h = b1[j] + dist*w1[j];
    for (int a=0;a<64;a++) h += temb[a]*w1[(a+1)*32+j];
    sh_h[sub][j] = silu_f(h);
  }
  __syncthreads();
  if (e < E){
    float o = b2[j];
    for (int a=0;a<32;a++) o += sh_h[sub][a]*w2[a*32+j];
    ef[(size_t)e*32+j] = o;
    if (j==0) atomicAdd(&degf[Nl + dst[e]], 1.f);
  }
}

// ------- merged pack: conv_w3 Wss slice (+bias rows) and conv MLP w1/w2 -> fp16 frag order -------
__global__ void k_packAll(const float* __restrict__ w3, const float* __restrict__ b3,
                          const float* __restrict__ w1, const float* __restrict__ w2,
                          _Float16* __restrict__ wbh,
                          _Float16* __restrict__ w1p, _Float16* __restrict__ w2p, int L){
  int tot1 = L*128*2304;
  int tot2 = L*64*48;
  int tot3 = L*8*512;
  int tot4 = L*32*512;
  int total = tot1 + tot2 + tot3 + tot4;
  for (int idx = blockIdx.x*blockDim.x+threadIdx.x; idx < total; idx += gridDim.x*blockDim.x){
    if (idx < tot1){
      int r = idx % 2304; int q = idx / 2304;
      int kk = q & 127;   int l = q >> 7;
      float v = w3[(size_t)(l*128+kk)*11520 + r];
      int i = r / 48, o = r - i*48;
      int kp = i*128 + kk;
      int kblk = kp >> 5, p = kp & 31;
      int lane = ((p>>3)<<4) + (o & 15);
      int j = p & 7;
      int nt = o >> 4;
      wbh[((((size_t)l*NKB + kblk)*3 + nt)*64 + lane)*8 + j] = (_Float16)v;
    } else if (idx < tot1 + tot2){
      int i2 = idx - tot1;
      int o = i2 % 48; int q = i2 / 48;
      int ii = q & 63; int l = q >> 6;
      float v = (ii < 48) ? b3[(size_t)l*11520 + ii*48 + o] : 0.f;
      int kp = 6144 + ii;
      int kblk = kp >> 5, p = kp & 31;
      int lane = ((p>>3)<<4) + (o & 15);
      int j = p & 7;
      int nt = o >> 4;
      wbh[((((size_t)l*NKB + kblk)*3 + nt)*64 + lane)*8 + j] = (_Float16)v;
    } else if (idx < tot1 + tot2 + tot3){
      int i3 = idx - tot1 - tot2;
      int j = i3 & 7, lane = (i3>>3)&63, rest = i3>>9;
      int nt = rest & 7, l = rest >> 3;
      int k = (lane>>4)*8 + j, o = nt*16 + (lane&15);
      w1p[i3] = (_Float16)w1[((size_t)l*32 + k)*128 + o];
    } else {
      int i4 = idx - tot1 - tot2 - tot3;
      int j = i4 & 7, lane = (i4>>3)&63, rest = i4>>9;
      int nt = rest & 7, kb = (rest>>3)&3, l = rest >> 5;
      int k = kb*32 + (lane>>4)*8 + j, o = nt*16 + (lane&15);
      w2p[i4] = (_Float16)w2[((size_t)l*128 + k)*128 + o];
    }
  }
}

// ---------------- edge MLP via MFMA: 64 edges x 1 layer per block ----------------
__global__ __launch_bounds__(256) void k_mlp2(
    const float* __restrict__ ef,
    const _Float16* __restrict__ w1p, const float* __restrict__ b1a,
    const _Float16* __restrict__ w2p, const float* __restrict__ b2a,
    _Float16* __restrict__ m2h, int E){
  __shared__ __align__(16) _Float16 sef[64][40];
  __shared__ __align__(16) _Float16 shh[64][136];
  __shared__ float sb1[128], sb2[128];
  const int t = threadIdx.x, lane = t & 63, w = t >> 6;
  const int e0 = blockIdx.x * 64;
  const int l  = blockIdx.y;
  const _Float16* w1l = w1p + (size_t)l*4096;
  const _Float16* w2l = w2p + (size_t)l*16384;
  if (t < 128) sb1[t] = b1a[l*128 + t];
  else         sb2[t-128] = b2a[l*128 + (t-128)];
  {
    int row = t >> 2, g = t & 3;
    const float* p = ef + ((size_t)(e0+row))*32 + g*8;
    float4 p0 = *(const float4*)p, p1 = *(const float4*)(p+4);
    half8 hv;
    hv[0]=(_Float16)p0.x; hv[1]=(_Float16)p0.y; hv[2]=(_Float16)p0.z; hv[3]=(_Float16)p0.w;
    hv[4]=(_Float16)p1.x; hv[5]=(_Float16)p1.y; hv[6]=(_Float16)p1.z; hv[7]=(_Float16)p1.w;
    *(half8*)&sef[row][g*8] = hv;
  }
  __syncthreads();
  const int m = lane & 15, quad = lane >> 4;
  const int r = w*16 + m;
  half8 a1 = *(const half8*)&sef[r][quad*8];
  f32x4 acc1[8];
  #pragma unroll
  for (int nt=0; nt<8; nt++){
    half8 b = *(const half8*)(w1l + (nt*64 + lane)*8);
    f32x4 z = {0.f,0.f,0.f,0.f};
    acc1[nt] = __builtin_amdgcn_mfma_f32_16x16x32_f16(a1, b, z, 0,0,0);
  }
  #pragma unroll
  for (int nt=0; nt<8; nt++){
    float bv = sb1[nt*16 + m];
    #pragma unroll
    for (int rr=0; rr<4; rr++)
      shh[w*16 + quad*4 + rr][nt*16 + m] = (_Float16)silu_f(acc1[nt][rr] + bv);
  }
  __syncthreads();
  f32x4 acc2[8];
  #pragma unroll
  for (int nt=0;nt<8;nt++) acc2[nt] = (f32x4){0.f,0.f,0.f,0.f};
  #pragma unroll
  for (int kb=0; kb<4; kb++){
    half8 a2 = *(const half8*)&shh[r][kb*32 + quad*8];
    #pragma unroll
    for (int nt=0; nt<8; nt++){
      half8 b = *(const half8*)(w2l + ((size_t)(kb*8+nt)*64 + lane)*8);
      acc2[nt] = __builtin_amdgcn_mfma_f32_16x16x32_f16(a2, b, acc2[nt], 0,0,0);
    }
  }
  __syncthreads();
  #pragma unroll
  for (int nt=0; nt<8; nt++){
    float bv = sb2[nt*16 + m];
    #pragma unroll
    for (int rr=0; rr<4; rr++)
      shh[w*16 + quad*4 + rr][nt*16 + m] = (_Float16)silu_f(acc2[nt][rr] + bv);
  }
  __syncthreads();
  for (int q = t; q < 64*16; q += 256){
    int row = q >> 4, c = q & 15;
    half8 hv = *(const half8*)&shh[row][c*8];
    *(half8*)(m2h + ((size_t)l*E + e0 + row)*128 + c*8) = hv;
  }
}

// ---- hot kernel v7: 64 edges/block, 3 blocks/CU; deferred-BN se; A in regs; LDS for B ----
__global__ __launch_bounds__(256) void k_msg7(
    const _Float16* __restrict__ m2h, const float* __restrict__ s,
    const float* __restrict__ a_s, const float* __restrict__ bnlp,
    const float* __restrict__ gp, const float* __restrict__ bp, int apply, int N,
    const _Float16* __restrict__ wbh,
    const int* __restrict__ src, const int* __restrict__ dst,
    float* __restrict__ Sacc, int Nl){
  __shared__ __align__(16) _Float16 sB[2][KCH*1536];   // 2 x 12 KiB
  __shared__ __align__(16) _Float16 sseq[64][72];      // 9.2 KiB (se, zero-padded)
  __shared__ int sdst[64];
  __shared__ float ksc[48], kbs[48];
  const int t = threadIdx.x, lane = t & 63, w = t >> 6;
  const int e0 = blockIdx.x * 64;
  const int by = blockIdx.y;
  const int kb0 = by*32;
  const int kb1 = (by==KSPL-1) ? NKB : kb0+32;

  if (t < 48){
    if (apply){
      float su = bnlp[t], sq = bnlp[48+t];
      float mu  = su/(float)N;
      float var = sq/(float)N - mu*mu;
      float r = rsqrtf(var + 1e-5f);
      float sc = gp[t]*r;
      ksc[t] = sc; kbs[t] = bp[t] - mu*sc;
    } else { ksc[t]=0.f; kbs[t]=0.f; }
  }
  if (t < 64) sdst[t] = dst[e0+t];
  __syncthreads();

  for (int q = t; q < 64*9; q += 256){
    int e = q/9, g = q - e*9;
    half8 hv = {};
    if (g < 6){
      size_t base = (size_t)src[e0+e]*48 + g*8;
      const float* sp = s + base;
      if (apply){
        const float* ap = a_s + base;
        #pragma unroll
        for (int j=0;j<8;j++){
          int o = g*8+j;
          hv[j] = (_Float16)(sp[j] + ap[j]*ksc[o] + kbs[o]);
        }
      } else {
        #pragma unroll
        for (int j=0;j<8;j++) hv[j] = (_Float16)sp[j];
      }
    }
    *(half8*)&sseq[e][g*8] = hv;
  }

  const int m = lane & 15, quad = lane >> 4;
  const int r0 = w*16 + m;

  half8 f0[4];
  {
    const _Float16* base0 = m2h + (size_t)(e0+r0)*128 + quad*8;
    #pragma unroll
    for (int sub=0; sub<4; sub++) f0[sub] = *(const half8*)(base0 + sub*32);
  }

  auto stage = [&](int c){
    int kbase = kb0 + c*KCH;
    int nk = kb1 - kbase; if (nk > KCH) nk = KCH;
    int bytes = nk*3072;
    const char* g = (const char*)wbh + (size_t)kbase*3072;
    char* lb = (char*)sB[c&1];
    for (int off = w*1024; off < bytes; off += 4096){
      __builtin_amdgcn_global_load_lds(
        (const __attribute__((address_space(1))) void*)(g + off + (size_t)lane*16),
        (__attribute__((address_space(3))) void*)(lb + off), 16, 0, 0);
    }
  };
  stage(0);

  f32x4 acc0={0.f,0.f,0.f,0.f}, acc1={0.f,0.f,0.f,0.f}, acc2={0.f,0.f,0.f,0.f};

  const int nch = (kb1-kb0+KCH-1)/KCH;
  for (int c = 0; c < nch; c++){
    __syncthreads();              // drains stage(c)
    if (c+1 < nch) stage(c+1);    // prefetch next chunk into other buffer
    int kbase = kb0 + c*KCH;
    int kbn = kb1 - kbase; if (kbn > KCH) kbn = KCH;
    const _Float16* bb = sB[c&1];
    if (kbn == KCH && kbase < 192){
      int i = kbase >> 2;
      _Float16 sv0 = sseq[r0][i];
      half8 s0v = {sv0,sv0,sv0,sv0,sv0,sv0,sv0,sv0};
      #pragma unroll
      for (int kk = 0; kk < KCH; kk++){
        half8 a0 = f0[kk] * s0v;  // v_pk_mul_f16 x4
        const _Float16* bk = bb + kk*1536 + lane*8;
        half8 b0 = *(const half8*)(bk);
        half8 b1 = *(const half8*)(bk + 512);
        half8 b2 = *(const half8*)(bk + 1024);
        acc0 = __builtin_amdgcn_mfma_f32_16x16x32_f16(a0, b0, acc0, 0, 0, 0);
        acc1 = __builtin_amdgcn_mfma_f32_16x16x32_f16(a0, b1, acc1, 0, 0, 0);
        acc2 = __builtin_amdgcn_mfma_f32_16x16x32_f16(a0, b2, acc2, 0, 0, 0);
      }
    } else {
      for (int kk = 0; kk < kbn; kk++){
        int kblk = kbase + kk;
        int ib = ((kblk-192) << 5) + quad*8;
        half8 a0 = *(const half8*)&sseq[r0][ib];
        const _Float16* bk = bb + kk*1536 + lane*8;
        half8 b0 = *(const half8*)(bk);
        half8 b1 = *(const half8*)(bk + 512);
        half8 b2 = *(const half8*)(bk + 1024);
        acc0 = __builtin_amdgcn_mfma_f32_16x16x32_f16(a0, b0, acc0, 0, 0, 0);
        acc1 = __builtin_amdgcn_mfma_f32_16x16x32_f16(a0, b1, acc1, 0, 0, 0);
        acc2 = __builtin_amdgcn_mfma_f32_16x16x32_f16(a0, b2, acc2, 0, 0, 0);
      }
    }
  }
  #pragma unroll
  for (int r = 0; r < 4; r++){
    int el0 = w*16 + quad*4 + r;
    float* p0 = Sacc + (size_t)(Nl + sdst[el0])*48 + m;
    atomicAdd(p0 +  0, acc0[r]*I48);
    atomicAdd(p0 + 16, acc1[r]*I48);
    atomicAdd(p0 + 32, acc2[r]*I48);
  }
}

// ---- node update v3: reconstruct+persist s, self-term, a_s, BN sums, Sacc zero ----
__global__ __launch_bounds__(256) void k_node3(float* __restrict__ Sacc,
                       const float* __restrict__ degf,
                       float* __restrict__ s, const float* __restrict__ siw,
                       float* __restrict__ a_s,
                       const float* __restrict__ bnlp, const float* __restrict__ gp,
                       const float* __restrict__ bp, int apply,
                       float* __restrict__ bnl, int N){
  __shared__ float sh_s[16][48];
  __shared__ float sw[2304];
  __shared__ float csum[48], csq[48];
  __shared__ float ksc[48], kbs[48];
  int t = threadIdx.x;
  int n0 = blockIdx.x*16;
  if (t < 48){
    if (apply){
      float su = bnlp[t], sq = bnlp[48+t];
      float mu  = su/(float)N;
      float var = sq/(float)N - mu*mu;
      float r = rsqrtf(var + 1e-5f);
      float sc = gp[t]*r;
      ksc[t] = sc; kbs[t] = bp[t] - mu*sc;
    } else { ksc[t]=0.f; kbs[t]=0.f; }
    csum[t]=0.f; csq[t]=0.f;
  }
  for (int q=t;q<2304;q+=256) sw[q] = siw[q];
  __syncthreads();
  for (int q=t;q<768;q+=256){
    int nl=q/48, o=q-nl*48;
    size_t idx = (size_t)(n0+nl)*48+o;
    float v = s[idx];
    if (apply){
      v += a_s[idx]*ksc[o] + kbs[o];
      s[idx] = v;            // persist T_l
    }
    sh_s[nl][o] = v;
  }
  __syncthreads();
  int nl = t>>4;
  int ob = (t&15)*3;
  int n = n0+nl;
  float dg = degf[n]; if (dg < 1.f) dg = 1.f;
  float inv = 1.f/dg;
  #pragma unroll
  for (int j=0;j<3;j++){
    int o = ob+j;
    size_t idx = (size_t)n*48+o;
    float acc = 0.f;
    for (int i=0;i<48;i++) acc += sh_s[nl][i]*sw[i*48+o];
    float a = Sacc[idx]*inv + acc*I48;
    Sacc[idx] = 0.f;         // ready for next layer
    a_s[idx] = a;
    atomicAdd(&csum[o], a);
    atomicAdd(&csq[o], a*a);
  }
  __syncthreads();
  if (t<96) atomicAdd(&bnl[t], (t<48) ? csum[t] : csq[t-48]);
}

// ------- output with final deferred update: [0,0,0, (s_final @ out_ws)*I48] -------
__global__ void k_out2(const float* __restrict__ s, const float* __restrict__ a_s,
                       const float* __restrict__ bnlp, const float* __restrict__ gp,
                       const float* __restrict__ bp, int N,
                       const float* __restrict__ ows, float* __restrict__ out){
  __shared__ float sh_s[48];
  __shared__ float ksc[48], kbs[48];
  int n = blockIdx.x, t = threadIdx.x;
  if (t < 48){
    float su = bnlp[t], sq = bnlp[48+t];
    float mu  = su/(float)N;
    float var = sq/(float)N - mu*mu;
    float r = rsqrtf(var + 1e-5f);
    float sc = gp[t]*r;
    ksc[t] = sc; kbs[t] = bp[t] - mu*sc;
  }
  __syncthreads();
  if (t<48){
    size_t idx = (size_t)n*48+t;
    sh_s[t] = s[idx] + a_s[idx]*ksc[t] + kbs[t];
  }
  __syncthreads();
  float acc = 0.f;
  for (int i=0;i<48;i++) acc += sh_s[i]*ows[i*256+t];
  out[(size_t)n*259 + 3 + t] = acc*I48;
  if (t<3) out[(size_t)n*259 + t] = 0.f;
}

extern "C" void kernel_launch(void* const* d_in, const int* in_sizes, int n_in,
                              void* d_out, int out_size, void* d_ws, size_t ws_size,
                              hipStream_t stream){
  const float* protein_coords   = (const float*)d_in[0];
  const float* protein_features = (const float*)d_in[1];
  const float* ligand_coords    = (const float*)d_in[2];
  const float* ligand_features  = (const float*)d_in[3];
  const float* t_in    = (const float*)d_in[4];
  const float* te_w1   = (const float*)d_in[5];
  const float* te_b1   = (const float*)d_in[6];
  const float* te_w2   = (const float*)d_in[7];
  const float* te_b2   = (const float*)d_in[8];
  const float* te_ln_g = (const float*)d_in[9];
  const float* te_ln_b = (const float*)d_in[10];
  const float* pe_w1   = (const float*)d_in[11];
  const float* pe_b1   = (const float*)d_in[12];
  const float* pe_ln_g = (const float*)d_in[13];
  const float* pe_ln_b = (const float*)d_in[14];
  const float* pe_w2   = (const float*)d_in[15];
  const float* pe_b2   = (const float*)d_in[16];
  const float* le_w1   = (const float*)d_in[17];
  const float* le_b1   = (const float*)d_in[18];
  const float* le_ln_g = (const float*)d_in[19];
  const float* le_ln_b = (const float*)d_in[20];
  const float* le_w2   = (const float*)d_in[21];
  const float* le_b2   = (const float*)d_in[22];
  const float* sp_w    = (const float*)d_in[23];
  const float* sp_b    = (const float*)d_in[24];
  const float* emb_w   = (const float*)d_in[25];
  const float* ee_w1   = (const float*)d_in[26];
  const float* ee_b1   = (const float*)d_in[27];
  const float* ee_w2   = (const float*)d_in[28];
  const float* ee_b2   = (const float*)d_in[29];
  const float* conv_w1 = (const float*)d_in[30];
  const float* conv_b1 = (const float*)d_in[31];
  const float* conv_w2 = (const float*)d_in[32];
  const float* conv_b2 = (const float*)d_in[33];
  const float* conv_w3 = (const float*)d_in[34];
  const float* conv_b3 = (const float*)d_in[35];
  const float* bn_gs   = (const float*)d_in[36];
  const float* bn_bs   = (const float*)d_in[37];
  const float* si_ws   = (const float*)d_in[40];
  const float* out_ws  = (const float*)d_in[43];
  const int* edge_src  = (const int*)d_in[45];
  const int* edge_dst  = (const int*)d_in[46];

  int Np = in_sizes[0]/6;
  int Nl = in_sizes[2]/3;
  int E  = in_sizes[45];
  int N  = Nl+Np;
  int L  = in_sizes[36]/48;

  float* W = (float*)d_ws;
  size_t off = 0;
  auto alloc = [&](size_t n)->float*{ float* p = W+off; off += (n+63)&~(size_t)63; return p; };
  // degf, Sacc, bnb contiguous -> single startup memset
  float* degf  = alloc(N);
  float* Sacc  = alloc((size_t)N*48);
  float* bnb   = alloc((size_t)L*96);
  float* temb  = alloc(64);
  float* sbuf  = alloc((size_t)N*48);
  float* ef    = alloc((size_t)E*32);
  float* a_s   = alloc((size_t)N*48);
  _Float16* m2h = (_Float16*)alloc((size_t)L*E*128/2 + 64);
  _Float16* wbh = (_Float16*)alloc((size_t)L*NKB*1536/2 + 64);
  _Float16* w1p = (_Float16*)alloc((size_t)L*4096/2 + 64);
  _Float16* w2p = (_Float16*)alloc((size_t)L*16384/2 + 64);

  hipMemsetAsync(degf, 0, ((size_t)N + (size_t)N*48 + (size_t)L*96 + 192)*sizeof(float), stream);
  k_packAll<<<2048,256,0,stream>>>(conv_w3, conv_b3, conv_w1, conv_w2, wbh, w1p, w2p, L);
  k_temb<<<1,128,0,stream>>>(t_in, te_w1, te_b1, te_w2, te_b2, te_ln_g, te_ln_b, temb);
  k_encall<<<N,128,0,stream>>>(protein_features, ligand_features, Nl,
                               pe_w1, pe_b1, pe_ln_g, pe_ln_b, pe_w2, pe_b2,
                               le_w1, le_b1, le_ln_g, le_ln_b, le_w2, le_b2,
                               sp_w, sp_b, emb_w, sbuf);
  k_edge<<<(E+1)/2,64,0,stream>>>(ligand_coords, protein_coords, edge_src, edge_dst, temb,
                                  ee_w1, ee_b1, ee_w2, ee_b2, ef, degf, E, Nl);
  dim3 mlpg(E/64, L);
  k_mlp2<<<mlpg,256,0,stream>>>(ef, w1p, conv_b1, w2p, conv_b2, m2h, E);

  dim3 mgrid(E/64, KSPL);
  for (int l=0;l<L;l++){
    const float* bnlp = (l>0) ? (bnb + (l-1)*96) : bnb;
    const float* gp   = (l>0) ? (bn_gs + (l-1)*48) : bn_gs;
    const float* bp   = (l>0) ? (bn_bs + (l-1)*48) : bn_bs;
    int apply = (l>0) ? 1 : 0;
    k_msg7<<<mgrid,256,0,stream>>>(m2h + (size_t)l*E*128, sbuf, a_s, bnlp, gp, bp, apply, N,
                                   wbh + (size_t)l*NKB*1536, edge_src, edge_dst, Sacc, Nl);
    k_node3<<<N/16,256,0,stream>>>(Sacc, degf, sbuf, si_ws + (size_t)l*2304, a_s,
                                   bnlp, gp, bp, apply, bnb + l*96, N);
  }
  k_out2<<<Nl,256,0,stream>>>(sbuf, a_s, bnb + (L-1)*96, bn_gs + (L-1)*48, bn_bs + (L-1)*48,
                              N, out_ws, (float*)d_out);
}